// Round 1
// baseline (6767.789 us; speedup 1.0000x reference)
//
#include <hip/hip_runtime.h>
#include <hip/hip_bf16.h>
#include <math.h>

#define B_ 4
#define S_ 512
#define D_ 512
#define F_ 2048
#define L_ 6
#define H_ 8
#define HD_ 64
#define V_ 32000

// ---------------------------------------------------------------------------
// Embedding: out[row, :] = emb[tok[row], :]*scale + pos[row % S, :]
// grid = B*S blocks, 256 threads (each handles 2 of 512 dims)
// ---------------------------------------------------------------------------
__global__ __launch_bounds__(256)
void embed_kernel(const int* __restrict__ tok, const float* __restrict__ emb,
                  const float* __restrict__ pos, float* __restrict__ out, float scale)
{
    int row = blockIdx.x;           // b*S + s
    int s = row & (S_ - 1);
    int t = tok[row];
    const float* er = emb + (long)t * D_;
    const float* pr = pos + (long)s * D_;
    float* o = out + (long)row * D_;
    int i = threadIdx.x;
    o[i]       = er[i]       * scale + pr[i];
    o[i + 256] = er[i + 256] * scale + pr[i + 256];
}

// ---------------------------------------------------------------------------
// Tiled fp32 GEMM: C = alpha * A * B (+bias) (+relu)
//  TRANSB==0: B is [K,N] row-major;  TRANSB==1: B is [N,K] row-major (C=A*B^T)
//  Batched via blockIdx.z: z -> (zb = z/Hdiv, zh = z%Hdiv), pointer offsets.
//  BM=BN=64, BK=32, 256 threads (16x16), each computes 4x4.
//  Requires M%64==0, N%64==0, K%32==0 (true for all shapes here).
// ---------------------------------------------------------------------------
template<int TRANSB, int RELU>
__global__ __launch_bounds__(256)
void gemm_kernel(const float* __restrict__ A, const float* __restrict__ B,
                 const float* __restrict__ bias, float* __restrict__ C,
                 int M, int N, int K, int lda, int ldb, int ldc,
                 long offA_b, long offA_h, long offB_b, long offB_h,
                 long offC_b, long offC_h, int Hdiv, float alpha)
{
    int z = blockIdx.z;
    int zb = z / Hdiv, zh = z % Hdiv;
    A += zb * offA_b + zh * offA_h;
    B += zb * offB_b + zh * offB_h;
    C += zb * offC_b + zh * offC_h;

    __shared__ float As[32][68];   // As[k][m]  (transposed A tile)
    __shared__ float Bs[32][68];   // Bs[k][n]

    const int tx = threadIdx.x, ty = threadIdx.y;
    const int tid = ty * 16 + tx;
    const int bm = blockIdx.y * 64, bn = blockIdx.x * 64;

    float acc[4][4] = {};

    for (int k0 = 0; k0 < K; k0 += 32) {
        // A tile 64x32 -> As[k][m] (global read contiguous in k)
        #pragma unroll
        for (int t = 0; t < 8; ++t) {
            int idx = tid + t * 256;
            int m = idx >> 5, kk = idx & 31;
            As[kk][m] = A[(long)(bm + m) * lda + k0 + kk];
        }
        if (TRANSB == 0) {
            // B tile 32x64 -> Bs[k][n] (global read contiguous in n)
            #pragma unroll
            for (int t = 0; t < 8; ++t) {
                int idx = tid + t * 256;
                int n = idx & 63, kk = idx >> 6;
                Bs[kk][n] = B[(long)(k0 + kk) * ldb + bn + n];
            }
        } else {
            // B tile (64 rows of N) x 32 (K) -> Bs[k][n] (contiguous in k)
            #pragma unroll
            for (int t = 0; t < 8; ++t) {
                int idx = tid + t * 256;
                int kk = idx & 31, n = idx >> 5;
                Bs[kk][n] = B[(long)(bn + n) * ldb + k0 + kk];
            }
        }
        __syncthreads();
        #pragma unroll
        for (int kk = 0; kk < 32; ++kk) {
            float4 a4 = *(const float4*)&As[kk][ty * 4];
            float4 b4 = *(const float4*)&Bs[kk][tx * 4];
            float av[4] = {a4.x, a4.y, a4.z, a4.w};
            float bv[4] = {b4.x, b4.y, b4.z, b4.w};
            #pragma unroll
            for (int i = 0; i < 4; ++i)
                #pragma unroll
                for (int j = 0; j < 4; ++j)
                    acc[i][j] += av[i] * bv[j];
        }
        __syncthreads();
    }

    #pragma unroll
    for (int i = 0; i < 4; ++i) {
        int row = bm + ty * 4 + i;
        float vj[4];
        #pragma unroll
        for (int j = 0; j < 4; ++j) {
            float v = acc[i][j] * alpha;
            if (bias) v += bias[bn + tx * 4 + j];
            if (RELU) v = fmaxf(v, 0.f);
            vj[j] = v;
        }
        *(float4*)&C[(long)row * ldc + bn + tx * 4] =
            make_float4(vj[0], vj[1], vj[2], vj[3]);
    }
}

// ---------------------------------------------------------------------------
// Masked softmax over last dim (S=512) of scores [B*H, S, S], in place.
// Mask from token ids: blocked if tok[b,k]==0, plus (causal) k > q.
// grid = (S, B*H), 256 threads (2 elems each).
// ---------------------------------------------------------------------------
__global__ __launch_bounds__(256)
void softmax_kernel(float* __restrict__ sc, const int* __restrict__ tok, int causal)
{
    int q = blockIdx.x;
    int bh = blockIdx.y;
    int b = bh >> 3;                 // / H_
    float* row = sc + ((long)bh * S_ + q) * S_;
    const int* tb = tok + b * S_;
    int t = threadIdx.x, t2 = t + 256;

    float v0 = row[t], v1 = row[t2];
    if (tb[t]  == 0 || (causal && t  > q)) v0 -= 1e9f;
    if (tb[t2] == 0 || (causal && t2 > q)) v1 -= 1e9f;

    float m = fmaxf(v0, v1);
    #pragma unroll
    for (int i = 1; i < 64; i <<= 1) m = fmaxf(m, __shfl_xor(m, i));
    __shared__ float rm[4], rs[4];
    int wid = t >> 6;
    if ((t & 63) == 0) rm[wid] = m;
    __syncthreads();
    m = fmaxf(fmaxf(rm[0], rm[1]), fmaxf(rm[2], rm[3]));

    float e0 = __expf(v0 - m), e1 = __expf(v1 - m);
    float s = e0 + e1;
    #pragma unroll
    for (int i = 1; i < 64; i <<= 1) s += __shfl_xor(s, i);
    if ((t & 63) == 0) rs[wid] = s;
    __syncthreads();
    s = rs[0] + rs[1] + rs[2] + rs[3];

    float inv = 1.f / s;
    row[t]  = e0 * inv;
    row[t2] = e1 * inv;
}

// ---------------------------------------------------------------------------
// x = LayerNorm(x + y) * g + b, rows of length D=512. grid=B*S, 256 threads.
// ---------------------------------------------------------------------------
__global__ __launch_bounds__(256)
void add_ln_kernel(float* __restrict__ x, const float* __restrict__ y,
                   const float* __restrict__ g, const float* __restrict__ bb)
{
    long row = blockIdx.x;
    float* xr = x + row * D_;
    const float* yr = y + row * D_;
    int t = threadIdx.x, t2 = t + 256;

    float r0 = xr[t] + yr[t];
    float r1 = xr[t2] + yr[t2];
    float s = r0 + r1;
    float s2 = r0 * r0 + r1 * r1;
    #pragma unroll
    for (int i = 1; i < 64; i <<= 1) {
        s  += __shfl_xor(s, i);
        s2 += __shfl_xor(s2, i);
    }
    __shared__ float rs[4], rs2[4];
    int wid = t >> 6;
    if ((t & 63) == 0) { rs[wid] = s; rs2[wid] = s2; }
    __syncthreads();
    s  = rs[0] + rs[1] + rs[2] + rs[3];
    s2 = rs2[0] + rs2[1] + rs2[2] + rs2[3];

    float mean = s * (1.f / D_);
    float var  = s2 * (1.f / D_) - mean * mean;
    float inv  = rsqrtf(var + 1e-6f);
    xr[t]  = (r0 - mean) * inv * g[t]  + bb[t];
    xr[t2] = (r1 - mean) * inv * g[t2] + bb[t2];
}

// ---------------------------------------------------------------------------
// Host-side helpers
// ---------------------------------------------------------------------------
static void launch_gemm(hipStream_t st, const float* A, const float* B,
                        const float* bias, float* C,
                        int M, int N, int K, int lda, int ldb, int ldc,
                        bool transb, bool relu,
                        int batches, int Hdiv,
                        long oAb, long oAh, long oBb, long oBh, long oCb, long oCh,
                        float alpha)
{
    dim3 grid(N / 64, M / 64, batches), blk(16, 16);
    if (transb) {
        if (relu) gemm_kernel<1,1><<<grid, blk, 0, st>>>(A,B,bias,C,M,N,K,lda,ldb,ldc,oAb,oAh,oBb,oBh,oCb,oCh,Hdiv,alpha);
        else      gemm_kernel<1,0><<<grid, blk, 0, st>>>(A,B,bias,C,M,N,K,lda,ldb,ldc,oAb,oAh,oBb,oBh,oCb,oCh,Hdiv,alpha);
    } else {
        if (relu) gemm_kernel<0,1><<<grid, blk, 0, st>>>(A,B,bias,C,M,N,K,lda,ldb,ldc,oAb,oAh,oBb,oBh,oCb,oCh,Hdiv,alpha);
        else      gemm_kernel<0,0><<<grid, blk, 0, st>>>(A,B,bias,C,M,N,K,lda,ldb,ldc,oAb,oAh,oBb,oBh,oCb,oCh,Hdiv,alpha);
    }
}

extern "C" void kernel_launch(void* const* d_in, const int* in_sizes, int n_in,
                              void* d_out, int out_size, void* d_ws, size_t ws_size,
                              hipStream_t stream)
{
    const int*   enc_in     = (const int*)  d_in[0];
    const int*   dec_in     = (const int*)  d_in[1];
    const float* e_embed    = (const float*)d_in[2];
    const float* d_embed    = (const float*)d_in[3];
    const float* pos_enc    = (const float*)d_in[4];
    const float* enc_mha_W  = (const float*)d_in[5];
    const float* enc_mha_b  = (const float*)d_in[6];
    const float* enc_ln_g   = (const float*)d_in[7];
    const float* enc_ln_b   = (const float*)d_in[8];
    const float* enc_ffn_W1 = (const float*)d_in[9];
    const float* enc_ffn_b1 = (const float*)d_in[10];
    const float* enc_ffn_W2 = (const float*)d_in[11];
    const float* enc_ffn_b2 = (const float*)d_in[12];
    const float* dec_mha_W  = (const float*)d_in[13];
    const float* dec_mha_b  = (const float*)d_in[14];
    const float* dec_ln_g   = (const float*)d_in[15];
    const float* dec_ln_b   = (const float*)d_in[16];
    const float* dec_ffn_W1 = (const float*)d_in[17];
    const float* dec_ffn_b1 = (const float*)d_in[18];
    const float* dec_ffn_W2 = (const float*)d_in[19];
    const float* dec_ffn_b2 = (const float*)d_in[20];
    float* out = (float*)d_out;

    const int  BS  = B_ * S_;                 // 2048
    const long BSD = (long)BS * D_;           // 1,048,576 floats
    const long DD  = (long)D_ * D_;
    const long SD  = (long)S_ * D_;
    const long SS  = (long)S_ * S_;

    float* ws  = (float*)d_ws;
    float* e   = ws;                // encoder state   [B,S,D]
    float* dd  = e  + BSD;          // decoder state   [B,T,D]
    float* yb  = dd + BSD;          // attn out / ffn out
    float* qb  = yb + BSD;          // q proj / proj out
    float* kb  = qb + BSD;          // k proj
    float* vb  = kb + BSD;          // v proj
    float* big = vb + BSD;          // scores [B*H,S,S] (32MB) or ffn hidden (16MB)

    const float scale = sqrtf((float)D_);
    embed_kernel<<<BS, 256, 0, stream>>>(enc_in, e_embed, pos_enc, e,  scale);
    embed_kernel<<<BS, 256, 0, stream>>>(dec_in, d_embed, pos_enc, dd, scale);

    dim3 smg(S_, B_ * H_);

    // ---------------- encoder ----------------
    for (int l = 0; l < L_; ++l) {
        const float* W  = enc_mha_W + (long)l * 4 * DD;
        const float* bW = enc_mha_b + (long)l * 4 * D_;
        launch_gemm(stream, e, W,        bW,        qb, BS, D_, D_, D_, D_, D_, false, false, 1,1, 0,0,0,0,0,0, 1.f);
        launch_gemm(stream, e, W + DD,   bW + D_,   kb, BS, D_, D_, D_, D_, D_, false, false, 1,1, 0,0,0,0,0,0, 1.f);
        launch_gemm(stream, e, W + 2*DD, bW + 2*D_, vb, BS, D_, D_, D_, D_, D_, false, false, 1,1, 0,0,0,0,0,0, 1.f);
        // scores = (q k^T) / 8 per (b,h)
        launch_gemm(stream, qb, kb, nullptr, big, S_, S_, HD_, D_, D_, S_, true, false,
                    B_ * H_, H_, SD, HD_, SD, HD_, (long)H_ * SS, SS, 0.125f);
        softmax_kernel<<<smg, 256, 0, stream>>>(big, enc_in, 0);
        // o = a @ v  -> yb (concat heads)
        launch_gemm(stream, big, vb, nullptr, yb, S_, HD_, S_, S_, D_, D_, false, false,
                    B_ * H_, H_, (long)H_ * SS, SS, SD, HD_, SD, HD_, 1.f);
        launch_gemm(stream, yb, W + 3*DD, bW + 3*D_, qb, BS, D_, D_, D_, D_, D_, false, false, 1,1, 0,0,0,0,0,0, 1.f);
        add_ln_kernel<<<BS, 256, 0, stream>>>(e, qb, enc_ln_g + (long)(l*2)*D_,   enc_ln_b + (long)(l*2)*D_);
        // FFN
        launch_gemm(stream, e, enc_ffn_W1 + (long)l*D_*F_, enc_ffn_b1 + (long)l*F_, big,
                    BS, F_, D_, D_, F_, F_, false, true, 1,1, 0,0,0,0,0,0, 1.f);
        launch_gemm(stream, big, enc_ffn_W2 + (long)l*F_*D_, enc_ffn_b2 + (long)l*D_, yb,
                    BS, D_, F_, F_, D_, D_, false, false, 1,1, 0,0,0,0,0,0, 1.f);
        add_ln_kernel<<<BS, 256, 0, stream>>>(e, yb, enc_ln_g + (long)(l*2+1)*D_, enc_ln_b + (long)(l*2+1)*D_);
    }

    // ---------------- decoder ----------------
    for (int l = 0; l < L_; ++l) {
        const float* W  = dec_mha_W + (long)l * 8 * DD;
        const float* bW = dec_mha_b + (long)l * 8 * D_;
        // self-attention (causal + pad)
        launch_gemm(stream, dd, W,        bW,        qb, BS, D_, D_, D_, D_, D_, false, false, 1,1, 0,0,0,0,0,0, 1.f);
        launch_gemm(stream, dd, W + DD,   bW + D_,   kb, BS, D_, D_, D_, D_, D_, false, false, 1,1, 0,0,0,0,0,0, 1.f);
        launch_gemm(stream, dd, W + 2*DD, bW + 2*D_, vb, BS, D_, D_, D_, D_, D_, false, false, 1,1, 0,0,0,0,0,0, 1.f);
        launch_gemm(stream, qb, kb, nullptr, big, S_, S_, HD_, D_, D_, S_, true, false,
                    B_ * H_, H_, SD, HD_, SD, HD_, (long)H_ * SS, SS, 0.125f);
        softmax_kernel<<<smg, 256, 0, stream>>>(big, dec_in, 1);
        launch_gemm(stream, big, vb, nullptr, yb, S_, HD_, S_, S_, D_, D_, false, false,
                    B_ * H_, H_, (long)H_ * SS, SS, SD, HD_, SD, HD_, 1.f);
        launch_gemm(stream, yb, W + 3*DD, bW + 3*D_, qb, BS, D_, D_, D_, D_, D_, false, false, 1,1, 0,0,0,0,0,0, 1.f);
        add_ln_kernel<<<BS, 256, 0, stream>>>(dd, qb, dec_ln_g + (long)(l*3)*D_,   dec_ln_b + (long)(l*3)*D_);
        // cross-attention (q from decoder, k/v from encoder, enc pad mask)
        launch_gemm(stream, dd, W + 4*DD, bW + 4*D_, qb, BS, D_, D_, D_, D_, D_, false, false, 1,1, 0,0,0,0,0,0, 1.f);
        launch_gemm(stream, e,  W + 5*DD, bW + 5*D_, kb, BS, D_, D_, D_, D_, D_, false, false, 1,1, 0,0,0,0,0,0, 1.f);
        launch_gemm(stream, e,  W + 6*DD, bW + 6*D_, vb, BS, D_, D_, D_, D_, D_, false, false, 1,1, 0,0,0,0,0,0, 1.f);
        launch_gemm(stream, qb, kb, nullptr, big, S_, S_, HD_, D_, D_, S_, true, false,
                    B_ * H_, H_, SD, HD_, SD, HD_, (long)H_ * SS, SS, 0.125f);
        softmax_kernel<<<smg, 256, 0, stream>>>(big, enc_in, 0);
        launch_gemm(stream, big, vb, nullptr, yb, S_, HD_, S_, S_, D_, D_, false, false,
                    B_ * H_, H_, (long)H_ * SS, SS, SD, HD_, SD, HD_, 1.f);
        launch_gemm(stream, yb, W + 7*DD, bW + 7*D_, qb, BS, D_, D_, D_, D_, D_, false, false, 1,1, 0,0,0,0,0,0, 1.f);
        add_ln_kernel<<<BS, 256, 0, stream>>>(dd, qb, dec_ln_g + (long)(l*3+1)*D_, dec_ln_b + (long)(l*3+1)*D_);
        // FFN
        launch_gemm(stream, dd, dec_ffn_W1 + (long)l*D_*F_, dec_ffn_b1 + (long)l*F_, big,
                    BS, F_, D_, D_, F_, F_, false, true, 1,1, 0,0,0,0,0,0, 1.f);
        launch_gemm(stream, big, dec_ffn_W2 + (long)l*F_*D_, dec_ffn_b2 + (long)l*D_, yb,
                    BS, D_, F_, F_, D_, D_, false, false, 1,1, 0,0,0,0,0,0, 1.f);
        add_ln_kernel<<<BS, 256, 0, stream>>>(dd, yb, dec_ln_g + (long)(l*3+2)*D_, dec_ln_b + (long)(l*3+2)*D_);
    }

    // ---------------- logits = dd @ d_embed^T ----------------
    launch_gemm(stream, dd, d_embed, nullptr, out, BS, V_, D_, D_, D_, V_, true, false,
                1, 1, 0,0,0,0,0,0, 1.f);
}

// Round 2
// 2564.129 us; speedup vs baseline: 2.6394x; 2.6394x over previous
//
#include <hip/hip_runtime.h>
#include <hip/hip_bf16.h>
#include <math.h>

#define B_ 4
#define S_ 512
#define D_ 512
#define F_ 2048
#define L_ 6
#define H_ 8
#define HD_ 64
#define V_ 32000

typedef unsigned short u16;
typedef __attribute__((ext_vector_type(8))) short bhalf8;   // 8 bf16 = 4 VGPRs
typedef __attribute__((ext_vector_type(4))) float f32x4;

__device__ __forceinline__ u16 f2b(float v) {
    unsigned x = __builtin_bit_cast(unsigned, v);
    return (u16)((x + 0x7FFFu + ((x >> 16) & 1u)) >> 16);   // RNE
}

#define GLD16(g, l) __builtin_amdgcn_global_load_lds( \
    (const __attribute__((address_space(1))) void*)(g), \
    (__attribute__((address_space(3))) void*)(l), 16, 0, 0)

// ---------------------------------------------------------------------------
// bf16 MFMA GEMM: C = alpha*A*B^T (+bias[col]) (+relu)
// A: [M][K] bf16 (row stride lda), B: [N][K] bf16 (row stride ldb, K-contig)
// BM=128 fixed, BN=128 (WC=2, 256thr) or BN=64 (WC=1, 128thr).
// Batched over blockIdx.z via (zb,zh) two-level offsets (z = zb*Hdiv+zh).
// OUT: 0 = fp32 C, 1 = bf16 C.
// ---------------------------------------------------------------------------
template<int BN, int WC, int OUT, int RELU>
__global__ __launch_bounds__(128 * WC)
void mfma_gemm(const u16* __restrict__ A, const u16* __restrict__ B,
               const float* __restrict__ bias, void* __restrict__ Cv,
               int K, int lda, int ldb, int ldc,
               long oAb, long oAh, long oBb, long oBh, long oCb, long oCh,
               int Hdiv, float alpha)
{
    constexpr int BM = 128;
    constexpr int NW = 2 * WC;
    constexpr int CH_A = BM / 16, CH_B = BN / 16, CH = CH_A + CH_B;

    const int z = blockIdx.z;
    const int zb = z / Hdiv, zh = z - zb * Hdiv;
    A += zb * oAb + zh * oAh;
    B += zb * oBb + zh * oBh;

    __shared__ u16 As[BM * 32];
    __shared__ u16 Bs[BN * 32];

    const int tid = threadIdx.x;
    const int wid = tid >> 6, lane = tid & 63;
    const int wrow = wid / WC, wcol = wid % WC;
    const long bm = (long)blockIdx.y * BM, bn = (long)blockIdx.x * BN;
    const int r4 = lane >> 2, c4 = lane & 3;

    f32x4 acc[4][4];
    #pragma unroll
    for (int i = 0; i < 4; ++i)
        #pragma unroll
        for (int j = 0; j < 4; ++j)
            acc[i][j] = (f32x4){0.f, 0.f, 0.f, 0.f};

    for (int k0 = 0; k0 < K; k0 += 32) {
        #pragma unroll
        for (int t = 0; t < CH / NW; ++t) {
            int c = wid + t * NW;
            if (c < CH_A) {
                const u16* g = A + (bm + c * 16 + r4) * (long)lda + k0 + c4 * 8;
                GLD16(g, As + c * 512 + lane * 8);
            } else {
                int cb = c - CH_A;
                const u16* g = B + (bn + cb * 16 + r4) * (long)ldb + k0 + c4 * 8;
                GLD16(g, Bs + cb * 512 + lane * 8);
            }
        }
        __syncthreads();
        bhalf8 af[4], bfr[4];
        #pragma unroll
        for (int i = 0; i < 4; ++i)
            af[i] = *(const bhalf8*)&As[(wrow * 64 + i * 16 + (lane & 15)) * 32 + (lane >> 4) * 8];
        #pragma unroll
        for (int j = 0; j < 4; ++j)
            bfr[j] = *(const bhalf8*)&Bs[(wcol * 64 + j * 16 + (lane & 15)) * 32 + (lane >> 4) * 8];
        #pragma unroll
        for (int i = 0; i < 4; ++i)
            #pragma unroll
            for (int j = 0; j < 4; ++j)
                acc[i][j] = __builtin_amdgcn_mfma_f32_16x16x32_bf16(af[i], bfr[j], acc[i][j], 0, 0, 0);
        __syncthreads();
    }

    float* Cf = (float*)Cv + zb * oCb + zh * oCh;
    u16*   Cb = (u16*)Cv  + zb * oCb + zh * oCh;
    const int rowb = wrow * 64 + ((lane >> 4) << 2);
    const int colb = wcol * 64 + (lane & 15);
    #pragma unroll
    for (int j = 0; j < 4; ++j) {
        const long gc = bn + colb + j * 16;
        const float bv = bias ? bias[gc] : 0.f;
        #pragma unroll
        for (int i = 0; i < 4; ++i) {
            const long gr = bm + rowb + i * 16;
            #pragma unroll
            for (int r = 0; r < 4; ++r) {
                float v = acc[i][j][r] * alpha + bv;
                if (RELU) v = fmaxf(v, 0.f);
                if (OUT == 0) Cf[(gr + r) * (long)ldc + gc] = v;
                else          Cb[(gr + r) * (long)ldc + gc] = f2b(v);
            }
        }
    }
}

// ---------------------------------------------------------------------------
// Weight prep: fp32 [R][C] -> bf16 [C][R] (transpose + convert), z-batched
// ---------------------------------------------------------------------------
__global__ __launch_bounds__(256)
void transpose_w(const float* __restrict__ in, u16* __restrict__ out,
                 int R, int C, long zi, long zo)
{
    in  += (long)blockIdx.z * zi;
    out += (long)blockIdx.z * zo;
    __shared__ float t[64][65];
    const int tr = blockIdx.y * 64, tc = blockIdx.x * 64;
    const int col = threadIdx.x & 63, r0 = threadIdx.x >> 6;
    #pragma unroll
    for (int p = 0; p < 16; ++p) {
        int row = r0 * 16 + p;
        t[row][col] = in[(long)(tr + row) * C + tc + col];
    }
    __syncthreads();
    #pragma unroll
    for (int p = 0; p < 16; ++p) {
        int row = r0 * 16 + p;
        out[(long)(tc + row) * R + tr + col] = f2b(t[col][row]);
    }
}

// bf16 [R][C] (row stride ldin) -> bf16 [C][R]
__global__ __launch_bounds__(256)
void transpose_b16(const u16* __restrict__ in, u16* __restrict__ out,
                   int ldin, int R, int C)
{
    __shared__ u16 t[64][65];
    const int tr = blockIdx.y * 64, tc = blockIdx.x * 64;
    const int col = threadIdx.x & 63, r0 = threadIdx.x >> 6;
    #pragma unroll
    for (int p = 0; p < 16; ++p) {
        int row = r0 * 16 + p;
        t[row][col] = in[(long)(tr + row) * ldin + tc + col];
    }
    __syncthreads();
    #pragma unroll
    for (int p = 0; p < 16; ++p) {
        int row = r0 * 16 + p;
        out[(long)(tc + row) * R + tr + col] = t[col][row];
    }
}

// fp32 -> bf16 flat convert (4 elems/thread)
__global__ __launch_bounds__(256)
void convert_b16(const float4* __restrict__ in, u16* __restrict__ out, long n4)
{
    long i = (long)blockIdx.x * 256 + threadIdx.x;
    if (i >= n4) return;
    float4 v = in[i];
    uint2 p;
    p.x = (unsigned)f2b(v.x) | ((unsigned)f2b(v.y) << 16);
    p.y = (unsigned)f2b(v.z) | ((unsigned)f2b(v.w) << 16);
    *(uint2*)(out + i * 4) = p;
}

// ---------------------------------------------------------------------------
// Embedding: x = emb[tok]*scale + pos, also bf16 copy
// ---------------------------------------------------------------------------
__global__ __launch_bounds__(256)
void embed_kernel(const int* __restrict__ tok, const float* __restrict__ emb,
                  const float* __restrict__ pos, float* __restrict__ x,
                  u16* __restrict__ xb, float scale)
{
    int row = blockIdx.x;
    int s = row & (S_ - 1);
    int t = tok[row];
    const float* er = emb + (long)t * D_;
    const float* pr = pos + (long)s * D_;
    float* o = x + (long)row * D_;
    u16*  ob = xb + (long)row * D_;
    int i = threadIdx.x;
    float v0 = er[i]       * scale + pr[i];
    float v1 = er[i + 256] * scale + pr[i + 256];
    o[i] = v0;       o[i + 256] = v1;
    ob[i] = f2b(v0); ob[i + 256] = f2b(v1);
}

// ---------------------------------------------------------------------------
// Masked softmax: fp32 scores [B*H,S,S] -> bf16 probs, mask from token ids
// ---------------------------------------------------------------------------
__global__ __launch_bounds__(256)
void softmax_kernel(const float* __restrict__ sc, u16* __restrict__ pr,
                    const int* __restrict__ tok, int causal)
{
    int q = blockIdx.x, bh = blockIdx.y, b = bh >> 3;
    const float* row = sc + ((long)bh * S_ + q) * S_;
    u16* orow = pr + ((long)bh * S_ + q) * S_;
    const int* tb = tok + b * S_;
    int t = threadIdx.x, t2 = t + 256;

    float v0 = row[t], v1 = row[t2];
    if (tb[t]  == 0 || (causal && t  > q)) v0 -= 1e9f;
    if (tb[t2] == 0 || (causal && t2 > q)) v1 -= 1e9f;

    float m = fmaxf(v0, v1);
    #pragma unroll
    for (int i = 1; i < 64; i <<= 1) m = fmaxf(m, __shfl_xor(m, i));
    __shared__ float rm[4], rs[4];
    int wid = t >> 6;
    if ((t & 63) == 0) rm[wid] = m;
    __syncthreads();
    m = fmaxf(fmaxf(rm[0], rm[1]), fmaxf(rm[2], rm[3]));

    float e0 = __expf(v0 - m), e1 = __expf(v1 - m);
    float s = e0 + e1;
    #pragma unroll
    for (int i = 1; i < 64; i <<= 1) s += __shfl_xor(s, i);
    if ((t & 63) == 0) rs[wid] = s;
    __syncthreads();
    s = rs[0] + rs[1] + rs[2] + rs[3];

    float inv = 1.f / s;
    orow[t]  = f2b(e0 * inv);
    orow[t2] = f2b(e1 * inv);
}

// ---------------------------------------------------------------------------
// x = LayerNorm(x + y) * g + b (fp32 state) + bf16 copy
// ---------------------------------------------------------------------------
__global__ __launch_bounds__(256)
void add_ln_kernel(float* __restrict__ x, const float* __restrict__ y,
                   u16* __restrict__ xb,
                   const float* __restrict__ g, const float* __restrict__ bb)
{
    long row = blockIdx.x;
    float* xr = x + row * D_;
    u16* xo = xb + row * D_;
    const float* yr = y + row * D_;
    int t = threadIdx.x, t2 = t + 256;

    float r0 = xr[t] + yr[t];
    float r1 = xr[t2] + yr[t2];
    float s = r0 + r1;
    float s2 = r0 * r0 + r1 * r1;
    #pragma unroll
    for (int i = 1; i < 64; i <<= 1) {
        s  += __shfl_xor(s, i);
        s2 += __shfl_xor(s2, i);
    }
    __shared__ float rs[4], rs2[4];
    int wid = t >> 6;
    if ((t & 63) == 0) { rs[wid] = s; rs2[wid] = s2; }
    __syncthreads();
    s  = rs[0] + rs[1] + rs[2] + rs[3];
    s2 = rs2[0] + rs2[1] + rs2[2] + rs2[3];

    float mean = s * (1.f / D_);
    float var  = s2 * (1.f / D_) - mean * mean;
    float inv  = rsqrtf(var + 1e-6f);
    float o0 = (r0 - mean) * inv * g[t]  + bb[t];
    float o1 = (r1 - mean) * inv * g[t2] + bb[t2];
    xr[t] = o0;       xr[t2] = o1;
    xo[t] = f2b(o0);  xo[t2] = f2b(o1);
}

// ---------------------------------------------------------------------------
// Host side
// ---------------------------------------------------------------------------
static void g128(hipStream_t st, int OUT, int RELU, dim3 grid,
                 const u16* A, const u16* B, const float* bias, void* C,
                 int K, int lda, int ldb, int ldc,
                 long oAb, long oAh, long oBb, long oBh, long oCb, long oCh,
                 int Hdiv, float alpha)
{
    dim3 blk(256);
    if (OUT == 0)
        mfma_gemm<128,2,0,0><<<grid, blk, 0, st>>>(A,B,bias,C,K,lda,ldb,ldc,oAb,oAh,oBb,oBh,oCb,oCh,Hdiv,alpha);
    else if (RELU)
        mfma_gemm<128,2,1,1><<<grid, blk, 0, st>>>(A,B,bias,C,K,lda,ldb,ldc,oAb,oAh,oBb,oBh,oCb,oCh,Hdiv,alpha);
    else
        mfma_gemm<128,2,1,0><<<grid, blk, 0, st>>>(A,B,bias,C,K,lda,ldb,ldc,oAb,oAh,oBb,oBh,oCb,oCh,Hdiv,alpha);
}

extern "C" void kernel_launch(void* const* d_in, const int* in_sizes, int n_in,
                              void* d_out, int out_size, void* d_ws, size_t ws_size,
                              hipStream_t stream)
{
    const int*   enc_in     = (const int*)  d_in[0];
    const int*   dec_in     = (const int*)  d_in[1];
    const float* e_embed    = (const float*)d_in[2];
    const float* d_embed    = (const float*)d_in[3];
    const float* pos_enc    = (const float*)d_in[4];
    const float* enc_mha_W  = (const float*)d_in[5];
    const float* enc_mha_b  = (const float*)d_in[6];
    const float* enc_ln_g   = (const float*)d_in[7];
    const float* enc_ln_b   = (const float*)d_in[8];
    const float* enc_ffn_W1 = (const float*)d_in[9];
    const float* enc_ffn_b1 = (const float*)d_in[10];
    const float* enc_ffn_W2 = (const float*)d_in[11];
    const float* enc_ffn_b2 = (const float*)d_in[12];
    const float* dec_mha_W  = (const float*)d_in[13];
    const float* dec_mha_b  = (const float*)d_in[14];
    const float* dec_ln_g   = (const float*)d_in[15];
    const float* dec_ln_b   = (const float*)d_in[16];
    const float* dec_ffn_W1 = (const float*)d_in[17];
    const float* dec_ffn_b1 = (const float*)d_in[18];
    const float* dec_ffn_W2 = (const float*)d_in[19];
    const float* dec_ffn_b2 = (const float*)d_in[20];
    float* out = (float*)d_out;

    const int  BS  = B_ * S_;                 // 2048
    const long BSD = (long)BS * D_;
    const long DD  = (long)D_ * D_;
    const long SS  = (long)S_ * S_;
    const long DF  = (long)D_ * F_;

    char* p = (char*)d_ws;
    auto alloc = [&](long bytes) { char* r = p; p += (bytes + 255) & ~255L; return r; };
    float* e      = (float*)alloc(BSD * 4);
    float* dd     = (float*)alloc(BSD * 4);
    float* y      = (float*)alloc(BSD * 4);
    u16*   eb     = (u16*)  alloc(BSD * 2);
    u16*   ddb    = (u16*)  alloc(BSD * 2);
    u16*   qkv    = (u16*)  alloc((long)BS * 1536 * 2);
    u16*   qc     = (u16*)  alloc(BSD * 2);
    u16*   att    = (u16*)  alloc(BSD * 2);
    u16*   vt     = (u16*)  alloc(BSD * 2);
    float* scores = (float*)alloc(32 * SS * 4);
    u16*   probs  = (u16*)  alloc(32 * SS * 2);
    u16*   wEmb   = (u16*)  alloc((long)V_ * D_ * 2);
    u16*   wEncMha= (u16*)  alloc(24 * DD * 2);
    u16*   wDecMha= (u16*)  alloc(48 * DD * 2);
    u16*   wEncF1 = (u16*)  alloc(6 * DF * 2);
    u16*   wEncF2 = (u16*)  alloc(6 * DF * 2);
    u16*   wDecF1 = (u16*)  alloc(6 * DF * 2);
    u16*   wDecF2 = (u16*)  alloc(6 * DF * 2);
    u16*   ffnh   = (u16*)scores;   // alias: FFN hidden reuses scores region

    // ---- weight prep: transpose+convert to bf16 [N][K] ----
    transpose_w<<<dim3(8, 8, 24), 256, 0, stream>>>(enc_mha_W, wEncMha, 512, 512, DD, DD);
    transpose_w<<<dim3(8, 8, 48), 256, 0, stream>>>(dec_mha_W, wDecMha, 512, 512, DD, DD);
    transpose_w<<<dim3(32, 8, 6), 256, 0, stream>>>(enc_ffn_W1, wEncF1, 512, 2048, DF, DF);
    transpose_w<<<dim3(8, 32, 6), 256, 0, stream>>>(enc_ffn_W2, wEncF2, 2048, 512, DF, DF);
    transpose_w<<<dim3(32, 8, 6), 256, 0, stream>>>(dec_ffn_W1, wDecF1, 512, 2048, DF, DF);
    transpose_w<<<dim3(8, 32, 6), 256, 0, stream>>>(dec_ffn_W2, wDecF2, 2048, 512, DF, DF);
    convert_b16<<<16000, 256, 0, stream>>>((const float4*)d_embed, wEmb, (long)V_ * D_ / 4);

    const float scale = sqrtf((float)D_);
    embed_kernel<<<BS, 256, 0, stream>>>(enc_in, e_embed, pos_enc, e,  eb,  scale);
    embed_kernel<<<BS, 256, 0, stream>>>(dec_in, d_embed, pos_enc, dd, ddb, scale);

    // ---------------- encoder ----------------
    for (int l = 0; l < L_; ++l) {
        const u16* Wl = wEncMha + (long)l * 4 * DD;
        const float* bl = enc_mha_b + (long)l * 4 * D_;
        // fused QKV: [2048][1536]
        g128(stream, 1, 0, dim3(12, 16, 1), eb, Wl, bl, qkv,
             512, 512, 512, 1536, 0,0,0,0,0,0, 1, 1.f);
        transpose_b16<<<dim3(8, 32), 256, 0, stream>>>(qkv + 1024, vt, 1536, 2048, 512);
        // scores = q k^T / 8, per (b,h)
        g128(stream, 0, 0, dim3(4, 4, 32), qkv, qkv + 512, nullptr, scores,
             64, 1536, 1536, 512,
             (long)512 * 1536, 64, (long)512 * 1536, 64, 8 * SS, SS, 8, 0.125f);
        softmax_kernel<<<dim3(512, 32), 256, 0, stream>>>(scores, probs, enc_in, 0);
        // att = probs @ v  (B = vt [64][2048] slice, TRANSB-natural)
        mfma_gemm<64,1,1,0><<<dim3(1, 4, 32), 128, 0, stream>>>(probs, vt, nullptr, att,
             512, 512, 2048, 512,
             8 * SS, SS, 512, (long)64 * 2048, (long)512 * 512, 64, 8, 1.f);
        // out projection -> fp32 y
        g128(stream, 0, 0, dim3(4, 16, 1), att, Wl + 3 * DD, bl + 3 * D_, y,
             512, 512, 512, 512, 0,0,0,0,0,0, 1, 1.f);
        add_ln_kernel<<<BS, 256, 0, stream>>>(e, y, eb,
             enc_ln_g + (long)(l * 2) * D_, enc_ln_b + (long)(l * 2) * D_);
        // FFN
        g128(stream, 1, 1, dim3(16, 16, 1), eb, wEncF1 + (long)l * DF,
             enc_ffn_b1 + (long)l * F_, ffnh, 512, 512, 512, 2048, 0,0,0,0,0,0, 1, 1.f);
        g128(stream, 0, 0, dim3(4, 16, 1), ffnh, wEncF2 + (long)l * DF,
             enc_ffn_b2 + (long)l * D_, y, 2048, 2048, 2048, 512, 0,0,0,0,0,0, 1, 1.f);
        add_ln_kernel<<<BS, 256, 0, stream>>>(e, y, eb,
             enc_ln_g + (long)(l * 2 + 1) * D_, enc_ln_b + (long)(l * 2 + 1) * D_);
    }

    // ---------------- decoder ----------------
    for (int l = 0; l < L_; ++l) {
        const u16* Wl = wDecMha + (long)l * 8 * DD;
        const float* bl = dec_mha_b + (long)l * 8 * D_;
        // self-attention (causal + dec pad)
        g128(stream, 1, 0, dim3(12, 16, 1), ddb, Wl, bl, qkv,
             512, 512, 512, 1536, 0,0,0,0,0,0, 1, 1.f);
        transpose_b16<<<dim3(8, 32), 256, 0, stream>>>(qkv + 1024, vt, 1536, 2048, 512);
        g128(stream, 0, 0, dim3(4, 4, 32), qkv, qkv + 512, nullptr, scores,
             64, 1536, 1536, 512,
             (long)512 * 1536, 64, (long)512 * 1536, 64, 8 * SS, SS, 8, 0.125f);
        softmax_kernel<<<dim3(512, 32), 256, 0, stream>>>(scores, probs, dec_in, 1);
        mfma_gemm<64,1,1,0><<<dim3(1, 4, 32), 128, 0, stream>>>(probs, vt, nullptr, att,
             512, 512, 2048, 512,
             8 * SS, SS, 512, (long)64 * 2048, (long)512 * 512, 64, 8, 1.f);
        g128(stream, 0, 0, dim3(4, 16, 1), att, Wl + 3 * DD, bl + 3 * D_, y,
             512, 512, 512, 512, 0,0,0,0,0,0, 1, 1.f);
        add_ln_kernel<<<BS, 256, 0, stream>>>(dd, y, ddb,
             dec_ln_g + (long)(l * 3) * D_, dec_ln_b + (long)(l * 3) * D_);
        // cross-attention (q from dec, k/v from enc, enc pad)
        g128(stream, 1, 0, dim3(4, 16, 1), ddb, Wl + 4 * DD, bl + 4 * D_, qc,
             512, 512, 512, 512, 0,0,0,0,0,0, 1, 1.f);
        g128(stream, 1, 0, dim3(8, 16, 1), eb, Wl + 5 * DD, bl + 5 * D_, qkv,
             512, 512, 512, 1024, 0,0,0,0,0,0, 1, 1.f);
        transpose_b16<<<dim3(8, 32), 256, 0, stream>>>(qkv + 512, vt, 1024, 2048, 512);
        g128(stream, 0, 0, dim3(4, 4, 32), qc, qkv, nullptr, scores,
             64, 512, 1024, 512,
             (long)512 * 512, 64, (long)512 * 1024, 64, 8 * SS, SS, 8, 0.125f);
        softmax_kernel<<<dim3(512, 32), 256, 0, stream>>>(scores, probs, enc_in, 0);
        mfma_gemm<64,1,1,0><<<dim3(1, 4, 32), 128, 0, stream>>>(probs, vt, nullptr, att,
             512, 512, 2048, 512,
             8 * SS, SS, 512, (long)64 * 2048, (long)512 * 512, 64, 8, 1.f);
        g128(stream, 0, 0, dim3(4, 16, 1), att, Wl + 7 * DD, bl + 7 * D_, y,
             512, 512, 512, 512, 0,0,0,0,0,0, 1, 1.f);
        add_ln_kernel<<<BS, 256, 0, stream>>>(dd, y, ddb,
             dec_ln_g + (long)(l * 3 + 1) * D_, dec_ln_b + (long)(l * 3 + 1) * D_);
        // FFN
        g128(stream, 1, 1, dim3(16, 16, 1), ddb, wDecF1 + (long)l * DF,
             dec_ffn_b1 + (long)l * F_, ffnh, 512, 512, 512, 2048, 0,0,0,0,0,0, 1, 1.f);
        g128(stream, 0, 0, dim3(4, 16, 1), ffnh, wDecF2 + (long)l * DF,
             dec_ffn_b2 + (long)l * D_, y, 2048, 2048, 2048, 512, 0,0,0,0,0,0, 1, 1.f);
        add_ln_kernel<<<BS, 256, 0, stream>>>(dd, y, ddb,
             dec_ln_g + (long)(l * 3 + 2) * D_, dec_ln_b + (long)(l * 3 + 2) * D_);
    }

    // ---------------- logits = dd @ d_embed^T ----------------
    g128(stream, 0, 0, dim3(250, 16, 1), ddb, wEmb, nullptr, out,
         512, 512, 512, 32000, 0,0,0,0,0,0, 1, 1.f);
}

// Round 3
// 2366.106 us; speedup vs baseline: 2.8603x; 1.0837x over previous
//
#include <hip/hip_runtime.h>
#include <hip/hip_bf16.h>
#include <math.h>

#define B_ 4
#define S_ 512
#define D_ 512
#define F_ 2048
#define L_ 6
#define H_ 8
#define V_ 32000

typedef unsigned short u16;
typedef __attribute__((ext_vector_type(8))) short bhalf8;   // 8 bf16 = 4 VGPRs
typedef __attribute__((ext_vector_type(4))) float f32x4;

__device__ __forceinline__ u16 f2b(float v) {
    unsigned x = __builtin_bit_cast(unsigned, v);
    return (u16)((x + 0x7FFFu + ((x >> 16) & 1u)) >> 16);   // RNE
}

#define GLD16(g, l) __builtin_amdgcn_global_load_lds( \
    (const __attribute__((address_space(1))) void*)(g), \
    (__attribute__((address_space(3))) void*)(l), 16, 0, 0)

__device__ __forceinline__ float redmax16(float v) {
    #pragma unroll
    for (int m = 1; m < 16; m <<= 1) v = fmaxf(v, __shfl_xor(v, m));
    return v;
}
__device__ __forceinline__ float redsum16(float v) {
    #pragma unroll
    for (int m = 1; m < 16; m <<= 1) v += __shfl_xor(v, m);
    return v;
}

// ---------------------------------------------------------------------------
// bf16 MFMA GEMM: C = A*B^T (+bias[col]) (+relu).  A:[M][K] lda, B:[N][K] ldb.
// BM=128; BN=128 (WC=2, 256thr) or BN=64 (WC=1, 128thr).
// vtp: columns >= vc0 are written TRANSPOSED (bf16) to vtp[(col-vc0)][row],
//      row-stride 2048 (V-cache for attention); they skip the normal C write.
// ---------------------------------------------------------------------------
template<int BN, int WC, int OUT, int RELU>
__global__ __launch_bounds__(128 * WC)
void mfma_gemm(const u16* __restrict__ A, const u16* __restrict__ B,
               const float* __restrict__ bias, void* __restrict__ Cv,
               int K, int lda, int ldb, int ldc,
               u16* __restrict__ vtp, int vc0)
{
    constexpr int BM = 128;
    constexpr int NW = 2 * WC;
    constexpr int CH_A = BM / 16, CH_B = BN / 16, CH = CH_A + CH_B;

    __shared__ u16 As[BM * 32];
    __shared__ u16 Bs[BN * 32];

    const int tid = threadIdx.x;
    const int wid = tid >> 6, lane = tid & 63;
    const int wrow = wid / WC, wcol = wid % WC;
    const long bm = (long)blockIdx.y * BM, bn = (long)blockIdx.x * BN;
    const int r4 = lane >> 2, c4 = lane & 3;
    const int l15 = lane & 15, l4 = lane >> 4;

    f32x4 acc[4][4];
    #pragma unroll
    for (int i = 0; i < 4; ++i)
        #pragma unroll
        for (int j = 0; j < 4; ++j)
            acc[i][j] = (f32x4){0.f, 0.f, 0.f, 0.f};

    for (int k0 = 0; k0 < K; k0 += 32) {
        #pragma unroll
        for (int t = 0; t < CH / NW; ++t) {
            int c = wid + t * NW;
            if (c < CH_A) {
                const u16* g = A + (bm + c * 16 + r4) * (long)lda + k0 + c4 * 8;
                GLD16(g, As + c * 512 + lane * 8);
            } else {
                int cb = c - CH_A;
                const u16* g = B + (bn + cb * 16 + r4) * (long)ldb + k0 + c4 * 8;
                GLD16(g, Bs + cb * 512 + lane * 8);
            }
        }
        __syncthreads();
        bhalf8 af[4], bfr[4];
        #pragma unroll
        for (int i = 0; i < 4; ++i)
            af[i] = *(const bhalf8*)&As[(wrow * 64 + i * 16 + l15) * 32 + l4 * 8];
        #pragma unroll
        for (int j = 0; j < 4; ++j)
            bfr[j] = *(const bhalf8*)&Bs[(wcol * 64 + j * 16 + l15) * 32 + l4 * 8];
        #pragma unroll
        for (int i = 0; i < 4; ++i)
            #pragma unroll
            for (int j = 0; j < 4; ++j)
                acc[i][j] = __builtin_amdgcn_mfma_f32_16x16x32_bf16(af[i], bfr[j], acc[i][j], 0, 0, 0);
        __syncthreads();
    }

    float* Cf = (float*)Cv;
    u16*   Cb = (u16*)Cv;
    const int rowb = wrow * 64 + (l4 << 2);
    const int colb = wcol * 64 + l15;
    #pragma unroll
    for (int j = 0; j < 4; ++j) {
        const long gcb = bn + wcol * 64 + j * 16;          // lane-uniform col block
        const bool tovt = (vtp != nullptr) && (gcb >= vc0);
        const long gc = bn + colb + j * 16;
        const float bv = bias ? bias[gc] : 0.f;
        #pragma unroll
        for (int i = 0; i < 4; ++i) {
            const long gr = bm + rowb + i * 16;
            #pragma unroll
            for (int r = 0; r < 4; ++r) {
                float v = acc[i][j][r] + bv;
                if (RELU) v = fmaxf(v, 0.f);
                if (tovt)          vtp[(gc - vc0) * 2048 + gr + r] = f2b(v);
                else if (OUT == 0) Cf[(gr + r) * (long)ldc + gc] = v;
                else               Cb[(gr + r) * (long)ldc + gc] = f2b(v);
            }
        }
    }
}

// ---------------------------------------------------------------------------
// Fused flash attention (one (b,h,qblock) per workgroup, 4 waves, 32 q each).
// Q:[tok][ldq] bf16 (head-offset pre-applied via h*64), K likewise,
// V from vt [512 d][2048 tok].  O -> att [tok][512] bf16.  scale=1/8 fused.
// K/V/Q staged via GLD16 with pre-swizzled global source (XOR chunk^row&7);
// P staged per-wave in swizzled LDS for the PV A-operand.
// ---------------------------------------------------------------------------
template<int CAUSAL>
__global__ __launch_bounds__(256)
void flash_kernel(const u16* __restrict__ Qp, int ldq,
                  const u16* __restrict__ Kp, int ldk,
                  const u16* __restrict__ Vt,
                  const int* __restrict__ tok,
                  u16* __restrict__ Op)
{
    __shared__ u16 QS[128 * 64];
    __shared__ u16 KS[64 * 64];
    __shared__ u16 VS[64 * 64];
    __shared__ u16 PS[4 * 32 * 64];
    __shared__ float MK[512];

    const int tid = threadIdx.x, lane = tid & 63, w = tid >> 6;
    const int l15 = lane & 15, l4 = lane >> 4;
    const int qb = blockIdx.x, bh = blockIdx.y;
    const int b = bh >> 3, h = bh & 7;

    const u16* Q = Qp + (long)(b * 512 + qb * 128) * ldq + h * 64;
    const u16* K = Kp + (long)(b * 512) * ldk + h * 64;
    const u16* V = Vt + (long)(h * 64) * 2048 + b * 512;
    u16* O = Op + (long)(b * 512 + qb * 128) * 512 + h * 64;

    {
        int t0 = tok[b * 512 + tid];
        int t1 = tok[b * 512 + 256 + tid];
        MK[tid]       = (t0 == 0) ? -1e9f : 0.f;
        MK[tid + 256] = (t1 == 0) ? -1e9f : 0.f;
    }
    {
        int r = tid >> 3;
        int c = (tid & 7) ^ (r & 7);
        #pragma unroll
        for (int t = 0; t < 4; ++t)
            GLD16(Q + (long)(t * 32 + r) * ldq + c * 8, QS + t * 2048 + tid * 8);
    }

    f32x4 oacc[2][4];
    float mrun[2][4], lrun[2][4];
    #pragma unroll
    for (int i = 0; i < 2; ++i)
        #pragma unroll
        for (int j = 0; j < 4; ++j)
            oacc[i][j] = (f32x4){0.f, 0.f, 0.f, 0.f};
    #pragma unroll
    for (int i = 0; i < 2; ++i)
        #pragma unroll
        for (int r = 0; r < 4; ++r) { mrun[i][r] = -1e30f; lrun[i][r] = 0.f; }

    bhalf8 qa[2][2];

    for (int t = 0; t < 8; ++t) {
        {
            int r = tid >> 3;
            int c = (tid & 7) ^ (r & 7);
            GLD16(K + (long)(t * 64 + r) * ldk + c * 8,      KS + tid * 8);
            GLD16(K + (long)(t * 64 + 32 + r) * ldk + c * 8, KS + 2048 + tid * 8);
            GLD16(V + (long)r * 2048 + t * 64 + c * 8,       VS + tid * 8);
            GLD16(V + (long)(r + 32) * 2048 + t * 64 + c * 8, VS + 2048 + tid * 8);
        }
        __syncthreads();
        if (t == 0) {
            #pragma unroll
            for (int i = 0; i < 2; ++i)
                #pragma unroll
                for (int kc = 0; kc < 2; ++kc) {
                    int row = w * 32 + i * 16 + l15;
                    qa[i][kc] = *(const bhalf8*)&QS[row * 64 + (((kc * 4 + l4) ^ (row & 7)) << 3)];
                }
        }
        // ---- S = Q K^T ----
        f32x4 sac[2][4];
        #pragma unroll
        for (int i = 0; i < 2; ++i)
            #pragma unroll
            for (int jj = 0; jj < 4; ++jj)
                sac[i][jj] = (f32x4){0.f, 0.f, 0.f, 0.f};
        bhalf8 kf[4][2];
        #pragma unroll
        for (int jj = 0; jj < 4; ++jj)
            #pragma unroll
            for (int kc = 0; kc < 2; ++kc) {
                int row = jj * 16 + l15;
                kf[jj][kc] = *(const bhalf8*)&KS[row * 64 + (((kc * 4 + l4) ^ (row & 7)) << 3)];
            }
        #pragma unroll
        for (int i = 0; i < 2; ++i)
            #pragma unroll
            for (int jj = 0; jj < 4; ++jj)
                #pragma unroll
                for (int kc = 0; kc < 2; ++kc)
                    sac[i][jj] = __builtin_amdgcn_mfma_f32_16x16x32_bf16(qa[i][kc], kf[jj][kc], sac[i][jj], 0, 0, 0);

        // ---- scale + mask ----
        #pragma unroll
        for (int i = 0; i < 2; ++i)
            #pragma unroll
            for (int jj = 0; jj < 4; ++jj) {
                float mk = MK[t * 64 + jj * 16 + l15];
                #pragma unroll
                for (int r = 0; r < 4; ++r) {
                    float mk2 = mk;
                    if (CAUSAL) {
                        int col = t * 64 + jj * 16 + l15;
                        int qr = qb * 128 + w * 32 + i * 16 + l4 * 4 + r;
                        if (col > qr) mk2 = -1e9f;
                    }
                    sac[i][jj][r] = sac[i][jj][r] * 0.125f + mk2;
                }
            }
        // ---- online softmax; write P (bf16) to per-wave swizzled LDS ----
        #pragma unroll
        for (int i = 0; i < 2; ++i)
            #pragma unroll
            for (int r = 0; r < 4; ++r) {
                float mx = fmaxf(fmaxf(sac[i][0][r], sac[i][1][r]),
                                 fmaxf(sac[i][2][r], sac[i][3][r]));
                mx = redmax16(mx);
                float mnew = fmaxf(mrun[i][r], mx);
                float alpha = __expf(mrun[i][r] - mnew);
                float sum = 0.f;
                int row_p = i * 16 + l4 * 4 + r;
                #pragma unroll
                for (int jj = 0; jj < 4; ++jj) {
                    float p = __expf(sac[i][jj][r] - mnew);
                    sum += p;
                    int kv = jj * 16 + l15;
                    PS[w * 2048 + row_p * 64 + ((((kv >> 3) ^ (row_p & 7)) << 3) | (kv & 7))] = f2b(p);
                }
                sum = redsum16(sum);
                lrun[i][r] = lrun[i][r] * alpha + sum;
                mrun[i][r] = mnew;
                #pragma unroll
                for (int jd = 0; jd < 4; ++jd) oacc[i][jd][r] *= alpha;
            }
        // ---- O += P V ----
        bhalf8 pa[2][2], vf[4][2];
        #pragma unroll
        for (int i = 0; i < 2; ++i)
            #pragma unroll
            for (int kc = 0; kc < 2; ++kc) {
                int row = i * 16 + l15;
                pa[i][kc] = *(const bhalf8*)&PS[w * 2048 + row * 64 + (((kc * 4 + l4) ^ (row & 7)) << 3)];
            }
        #pragma unroll
        for (int jd = 0; jd < 4; ++jd)
            #pragma unroll
            for (int kc = 0; kc < 2; ++kc) {
                int row = jd * 16 + l15;
                vf[jd][kc] = *(const bhalf8*)&VS[row * 64 + (((kc * 4 + l4) ^ (row & 7)) << 3)];
            }
        #pragma unroll
        for (int i = 0; i < 2; ++i)
            #pragma unroll
            for (int jd = 0; jd < 4; ++jd)
                #pragma unroll
                for (int kc = 0; kc < 2; ++kc)
                    oacc[i][jd] = __builtin_amdgcn_mfma_f32_16x16x32_bf16(pa[i][kc], vf[jd][kc], oacc[i][jd], 0, 0, 0);
        __syncthreads();
    }

    #pragma unroll
    for (int i = 0; i < 2; ++i)
        #pragma unroll
        for (int r = 0; r < 4; ++r) {
            float inv = 1.f / lrun[i][r];
            int row = w * 32 + i * 16 + l4 * 4 + r;
            #pragma unroll
            for (int jd = 0; jd < 4; ++jd)
                O[(long)row * 512 + jd * 16 + l15] = f2b(oacc[i][jd][r] * inv);
        }
}

// ---------------------------------------------------------------------------
// Prep: fp32 [R][C] -> bf16 [C][R] for a pack of matrices from two bases
// ---------------------------------------------------------------------------
__global__ __launch_bounds__(256)
void transpose_many(const float* __restrict__ inA, const float* __restrict__ inB,
                    int zsplit, int R, int C, u16* __restrict__ out)
{
    int z = blockIdx.z;
    const float* in = (z < zsplit) ? inA + (long)z * R * C
                                   : inB + (long)(z - zsplit) * R * C;
    u16* o = out + (long)z * R * C;
    __shared__ float tb[64][65];
    const int tr = blockIdx.y * 64, tc = blockIdx.x * 64;
    const int col = threadIdx.x & 63, r0 = threadIdx.x >> 6;
    #pragma unroll
    for (int p = 0; p < 16; ++p) {
        int row = r0 * 16 + p;
        tb[row][col] = in[(long)(tr + row) * C + tc + col];
    }
    __syncthreads();
    #pragma unroll
    for (int p = 0; p < 16; ++p) {
        int row = r0 * 16 + p;
        o[(long)(tc + row) * R + tr + col] = f2b(tb[col][row]);
    }
}

__global__ __launch_bounds__(256)
void convert_b16(const float4* __restrict__ in, u16* __restrict__ out, long n4)
{
    long i = (long)blockIdx.x * 256 + threadIdx.x;
    if (i >= n4) return;
    float4 v = in[i];
    uint2 p;
    p.x = (unsigned)f2b(v.x) | ((unsigned)f2b(v.y) << 16);
    p.y = (unsigned)f2b(v.z) | ((unsigned)f2b(v.w) << 16);
    *(uint2*)(out + i * 4) = p;
}

// ---------------------------------------------------------------------------
// Embedding (both sequences in one dispatch): x = emb[tok]*scale + pos
// ---------------------------------------------------------------------------
__global__ __launch_bounds__(256)
void embed_kernel(const int* __restrict__ tE, const int* __restrict__ tD,
                  const float* __restrict__ eE, const float* __restrict__ eD,
                  const float* __restrict__ pos,
                  float* __restrict__ xE, float* __restrict__ xD,
                  u16* __restrict__ bE, u16* __restrict__ bD, float scale)
{
    const int z = blockIdx.y;
    const int* tok = z ? tD : tE;
    const float* emb = z ? eD : eE;
    float* x = z ? xD : xE;
    u16* xb = z ? bD : bE;
    int row = blockIdx.x;
    int s = row & (S_ - 1);
    int t = tok[row];
    const float* er = emb + (long)t * D_;
    const float* pr = pos + (long)s * D_;
    float* o = x + (long)row * D_;
    u16*  ob = xb + (long)row * D_;
    int i = threadIdx.x;
    float v0 = er[i]       * scale + pr[i];
    float v1 = er[i + 256] * scale + pr[i + 256];
    o[i] = v0;        o[i + 256] = v1;
    ob[i] = f2b(v0);  ob[i + 256] = f2b(v1);
}

// ---------------------------------------------------------------------------
// x = LayerNorm(x + y) * g + b (fp32 state) + bf16 copy
// ---------------------------------------------------------------------------
__global__ __launch_bounds__(256)
void add_ln_kernel(float* __restrict__ x, const float* __restrict__ y,
                   u16* __restrict__ xb,
                   const float* __restrict__ g, const float* __restrict__ bb)
{
    long row = blockIdx.x;
    float* xr = x + row * D_;
    u16* xo = xb + row * D_;
    const float* yr = y + row * D_;
    int t = threadIdx.x, t2 = t + 256;

    float r0 = xr[t] + yr[t];
    float r1 = xr[t2] + yr[t2];
    float s = r0 + r1;
    float s2 = r0 * r0 + r1 * r1;
    #pragma unroll
    for (int i = 1; i < 64; i <<= 1) {
        s  += __shfl_xor(s, i);
        s2 += __shfl_xor(s2, i);
    }
    __shared__ float rs[4], rs2[4];
    int wid = t >> 6;
    if ((t & 63) == 0) { rs[wid] = s; rs2[wid] = s2; }
    __syncthreads();
    s  = rs[0] + rs[1] + rs[2] + rs[3];
    s2 = rs2[0] + rs2[1] + rs2[2] + rs2[3];

    float mean = s * (1.f / D_);
    float var  = s2 * (1.f / D_) - mean * mean;
    float inv  = rsqrtf(var + 1e-6f);
    float o0 = (r0 - mean) * inv * g[t]  + bb[t];
    float o1 = (r1 - mean) * inv * g[t2] + bb[t2];
    xr[t] = o0;       xr[t2] = o1;
    xo[t] = f2b(o0);  xo[t2] = f2b(o1);
}

// ---------------------------------------------------------------------------
extern "C" void kernel_launch(void* const* d_in, const int* in_sizes, int n_in,
                              void* d_out, int out_size, void* d_ws, size_t ws_size,
                              hipStream_t stream)
{
    const int*   enc_in     = (const int*)  d_in[0];
    const int*   dec_in     = (const int*)  d_in[1];
    const float* e_embed    = (const float*)d_in[2];
    const float* d_embed    = (const float*)d_in[3];
    const float* pos_enc    = (const float*)d_in[4];
    const float* enc_mha_W  = (const float*)d_in[5];
    const float* enc_mha_b  = (const float*)d_in[6];
    const float* enc_ln_g   = (const float*)d_in[7];
    const float* enc_ln_b   = (const float*)d_in[8];
    const float* enc_ffn_W1 = (const float*)d_in[9];
    const float* enc_ffn_b1 = (const float*)d_in[10];
    const float* enc_ffn_W2 = (const float*)d_in[11];
    const float* enc_ffn_b2 = (const float*)d_in[12];
    const float* dec_mha_W  = (const float*)d_in[13];
    const float* dec_mha_b  = (const float*)d_in[14];
    const float* dec_ln_g   = (const float*)d_in[15];
    const float* dec_ln_b   = (const float*)d_in[16];
    const float* dec_ffn_W1 = (const float*)d_in[17];
    const float* dec_ffn_b1 = (const float*)d_in[18];
    const float* dec_ffn_W2 = (const float*)d_in[19];
    const float* dec_ffn_b2 = (const float*)d_in[20];
    float* out = (float*)d_out;

    const int  BS  = B_ * S_;                 // 2048
    const long BSD = (long)BS * D_;
    const long DD  = (long)D_ * D_;
    const long DF  = (long)D_ * F_;

    char* p = (char*)d_ws;
    auto alloc = [&](long bytes) { char* r = p; p += (bytes + 255) & ~255L; return r; };
    float* e    = (float*)alloc(BSD * 4);
    float* dd   = (float*)alloc(BSD * 4);
    float* y    = (float*)alloc(BSD * 4);
    u16*   eb   = (u16*)  alloc(BSD * 2);
    u16*   ddb  = (u16*)  alloc(BSD * 2);
    u16*   qkv  = (u16*)  alloc((long)BS * 1536 * 2);
    u16*   qc   = (u16*)  alloc(BSD * 2);
    u16*   att  = (u16*)  alloc(BSD * 2);
    u16*   vt   = (u16*)  alloc(BSD * 2);
    u16*   ffnh = (u16*)  alloc((long)BS * F_ * 2);
    u16*   wEmb = (u16*)  alloc((long)V_ * D_ * 2);
    u16*   wMha = (u16*)  alloc(72 * DD * 2);
    u16*   wF1  = (u16*)  alloc(12 * DF * 2);
    u16*   wF2  = (u16*)  alloc(12 * DF * 2);

    // ---- weight prep ----
    transpose_many<<<dim3(8, 8, 72), 256, 0, stream>>>(enc_mha_W, dec_mha_W, 24, 512, 512, wMha);
    transpose_many<<<dim3(32, 8, 12), 256, 0, stream>>>(enc_ffn_W1, dec_ffn_W1, 6, 512, 2048, wF1);
    transpose_many<<<dim3(8, 32, 12), 256, 0, stream>>>(enc_ffn_W2, dec_ffn_W2, 6, 2048, 512, wF2);
    convert_b16<<<16000, 256, 0, stream>>>((const float4*)d_embed, wEmb, (long)V_ * D_ / 4);

    const float scale = sqrtf((float)D_);
    embed_kernel<<<dim3(BS, 2), 256, 0, stream>>>(enc_in, dec_in, e_embed, d_embed,
                                                  pos_enc, e, dd, eb, ddb, scale);

    // ---------------- encoder ----------------
    for (int l = 0; l < L_; ++l) {
        const u16* Wl = wMha + (long)l * 4 * DD;
        const float* bl = enc_mha_b + (long)l * 4 * D_;
        mfma_gemm<64,1,1,0><<<dim3(24, 16), 128, 0, stream>>>(eb, Wl, bl, qkv,
            512, 512, 512, 1536, vt, 1024);
        flash_kernel<0><<<dim3(4, 32), 256, 0, stream>>>(qkv, 1536, qkv + 512, 1536, vt, enc_in, att);
        mfma_gemm<64,1,0,0><<<dim3(8, 16), 128, 0, stream>>>(att, Wl + 3 * DD, bl + 3 * D_, y,
            512, 512, 512, 512, nullptr, 0);
        add_ln_kernel<<<BS, 256, 0, stream>>>(e, y, eb,
            enc_ln_g + (long)(l * 2) * D_, enc_ln_b + (long)(l * 2) * D_);
        mfma_gemm<128,2,1,1><<<dim3(16, 16), 256, 0, stream>>>(eb, wF1 + (long)l * DF,
            enc_ffn_b1 + (long)l * F_, ffnh, 512, 512, 512, 2048, nullptr, 0);
        mfma_gemm<64,1,0,0><<<dim3(8, 16), 128, 0, stream>>>(ffnh, wF2 + (long)l * DF,
            enc_ffn_b2 + (long)l * D_, y, 2048, 2048, 2048, 512, nullptr, 0);
        add_ln_kernel<<<BS, 256, 0, stream>>>(e, y, eb,
            enc_ln_g + (long)(l * 2 + 1) * D_, enc_ln_b + (long)(l * 2 + 1) * D_);
    }

    // ---------------- decoder ----------------
    for (int l = 0; l < L_; ++l) {
        const u16* Wl = wMha + (long)(24 + l * 8) * DD;
        const float* bl = dec_mha_b + (long)l * 8 * D_;
        // self-attention (causal + dec pad)
        mfma_gemm<64,1,1,0><<<dim3(24, 16), 128, 0, stream>>>(ddb, Wl, bl, qkv,
            512, 512, 512, 1536, vt, 1024);
        flash_kernel<1><<<dim3(4, 32), 256, 0, stream>>>(qkv, 1536, qkv + 512, 1536, vt, dec_in, att);
        mfma_gemm<64,1,0,0><<<dim3(8, 16), 128, 0, stream>>>(att, Wl + 3 * DD, bl + 3 * D_, y,
            512, 512, 512, 512, nullptr, 0);
        add_ln_kernel<<<BS, 256, 0, stream>>>(dd, y, ddb,
            dec_ln_g + (long)(l * 3) * D_, dec_ln_b + (long)(l * 3) * D_);
        // cross-attention (q from dec, k/v from enc final)
        mfma_gemm<64,1,1,0><<<dim3(8, 16), 128, 0, stream>>>(ddb, Wl + 4 * DD, bl + 4 * D_, qc,
            512, 512, 512, 512, nullptr, 0);
        mfma_gemm<64,1,1,0><<<dim3(16, 16), 128, 0, stream>>>(eb, Wl + 5 * DD, bl + 5 * D_, qkv,
            512, 512, 512, 1024, vt, 512);
        flash_kernel<0><<<dim3(4, 32), 256, 0, stream>>>(qc, 512, qkv, 1024, vt, enc_in, att);
        mfma_gemm<64,1,0,0><<<dim3(8, 16), 128, 0, stream>>>(att, Wl + 7 * DD, bl + 7 * D_, y,
            512, 512, 512, 512, nullptr, 0);
        add_ln_kernel<<<BS, 256, 0, stream>>>(dd, y, ddb,
            dec_ln_g + (long)(l * 3 + 1) * D_, dec_ln_b + (long)(l * 3 + 1) * D_);
        // FFN
        mfma_gemm<128,2,1,1><<<dim3(16, 16), 256, 0, stream>>>(ddb, wF1 + (long)(6 + l) * DF,
            dec_ffn_b1 + (long)l * F_, ffnh, 512, 512, 512, 2048, nullptr, 0);
        mfma_gemm<64,1,0,0><<<dim3(8, 16), 128, 0, stream>>>(ffnh, wF2 + (long)(6 + l) * DF,
            dec_ffn_b2 + (long)l * D_, y, 2048, 2048, 2048, 512, nullptr, 0);
        add_ln_kernel<<<BS, 256, 0, stream>>>(dd, y, ddb,
            dec_ln_g + (long)(l * 3 + 2) * D_, dec_ln_b + (long)(l * 3 + 2) * D_);
    }

    // ---------------- logits = dd @ d_embed^T ----------------
    mfma_gemm<128,2,0,0><<<dim3(250, 16), 256, 0, stream>>>(ddb, wEmb, nullptr, out,
        512, 512, 512, 32000, nullptr, 0);
}

// Round 4
// 1864.057 us; speedup vs baseline: 3.6307x; 1.2693x over previous
//
#include <hip/hip_runtime.h>
#include <hip/hip_bf16.h>
#include <math.h>

#define B_ 4
#define S_ 512
#define D_ 512
#define F_ 2048
#define L_ 6
#define H_ 8
#define V_ 32000

typedef unsigned short u16;
typedef __attribute__((ext_vector_type(8))) short bhalf8;   // 8 bf16 = 4 VGPRs
typedef __attribute__((ext_vector_type(4))) float f32x4;

__device__ __forceinline__ u16 f2b(float v) {
    unsigned x = __builtin_bit_cast(unsigned, v);
    return (u16)((x + 0x7FFFu + ((x >> 16) & 1u)) >> 16);   // RNE
}

#define GLD16(g, l) __builtin_amdgcn_global_load_lds( \
    (const __attribute__((address_space(1))) void*)(g), \
    (__attribute__((address_space(3))) void*)(l), 16, 0, 0)

__device__ __forceinline__ float redmax16(float v) {
    #pragma unroll
    for (int m = 1; m < 16; m <<= 1) v = fmaxf(v, __shfl_xor(v, m));
    return v;
}
__device__ __forceinline__ float redsum16(float v) {
    #pragma unroll
    for (int m = 1; m < 16; m <<= 1) v += __shfl_xor(v, m);
    return v;
}

// ---------------------------------------------------------------------------
// bf16 MFMA GEMM: C = A*B^T (+bias[col]) (+relu).
// A:[M][K] lda bf16; B:[N][K] ldb bf16 (K-contig).  Wave tile WM x WN,
// block = NWR x NWC waves -> BM = NWR*WM, BN = NWC*WN.
// MLOOP: block loops over MLOOP M-tiles (B panel stays hot in L2).
// SPLITA: blocks with bn >= acut use A2 instead of A (fused cross-attn projs).
// vtp: cols >= vc0 written transposed bf16 to vtp[(col-vc0)][row], stride 2048.
// ---------------------------------------------------------------------------
template<int NWR, int NWC, int WM, int WN, int OUT, int RELU, int MLOOP, int SPLITA>
__global__ __launch_bounds__(NWR * NWC * 64)
void mfma_gemm(const u16* __restrict__ A, const u16* __restrict__ A2, int acut,
               const u16* __restrict__ B,
               const float* __restrict__ bias, void* __restrict__ Cv,
               int K, int lda, int ldb, int ldc,
               u16* __restrict__ vtp, int vc0)
{
    constexpr int BM = NWR * WM, BN = NWC * WN;
    constexpr int NW = NWR * NWC;
    constexpr int CH_A = BM / 16, CH_B = BN / 16, CH = CH_A + CH_B;
    constexpr int NI = WM / 16, NJ = WN / 16;

    __shared__ u16 As[BM * 32];
    __shared__ u16 Bs[BN * 32];

    const int tid = threadIdx.x;
    const int wid = tid >> 6, lane = tid & 63;
    const int wrow = wid / NWC, wcol = wid % NWC;
    const long bn = (long)blockIdx.x * BN;
    const int r4 = lane >> 2, c4 = lane & 3;
    const int l15 = lane & 15, l4 = lane >> 4;

    const u16* Ause = (SPLITA && bn >= acut) ? A2 : A;

    #pragma unroll 1
    for (int mi = 0; mi < MLOOP; ++mi) {
        const long bm = ((long)blockIdx.y * MLOOP + mi) * BM;

        f32x4 acc[NI][NJ];
        #pragma unroll
        for (int i = 0; i < NI; ++i)
            #pragma unroll
            for (int j = 0; j < NJ; ++j)
                acc[i][j] = (f32x4){0.f, 0.f, 0.f, 0.f};

        for (int k0 = 0; k0 < K; k0 += 32) {
            #pragma unroll
            for (int t = 0; t < CH / NW; ++t) {
                int c = wid + t * NW;
                if (c < CH_A) {
                    const u16* g = Ause + (bm + c * 16 + r4) * (long)lda + k0 + c4 * 8;
                    GLD16(g, As + c * 512 + lane * 8);
                } else {
                    int cb = c - CH_A;
                    const u16* g = B + (bn + cb * 16 + r4) * (long)ldb + k0 + c4 * 8;
                    GLD16(g, Bs + cb * 512 + lane * 8);
                }
            }
            __syncthreads();
            bhalf8 af[NI], bfr[NJ];
            #pragma unroll
            for (int i = 0; i < NI; ++i)
                af[i] = *(const bhalf8*)&As[(wrow * WM + i * 16 + l15) * 32 + l4 * 8];
            #pragma unroll
            for (int j = 0; j < NJ; ++j)
                bfr[j] = *(const bhalf8*)&Bs[(wcol * WN + j * 16 + l15) * 32 + l4 * 8];
            #pragma unroll
            for (int i = 0; i < NI; ++i)
                #pragma unroll
                for (int j = 0; j < NJ; ++j)
                    acc[i][j] = __builtin_amdgcn_mfma_f32_16x16x32_bf16(af[i], bfr[j], acc[i][j], 0, 0, 0);
            __syncthreads();
        }

        float* Cf = (float*)Cv;
        u16*   Cb = (u16*)Cv;
        const int rowb = wrow * WM + (l4 << 2);
        const int colb = wcol * WN + l15;
        #pragma unroll
        for (int j = 0; j < NJ; ++j) {
            const long gcb = bn + wcol * WN + j * 16;      // lane-uniform col block
            const bool tovt = (vtp != nullptr) && (gcb >= vc0);
            const long gc = bn + colb + j * 16;
            const float bv = bias ? bias[gc] : 0.f;
            #pragma unroll
            for (int i = 0; i < NI; ++i) {
                const long gr = bm + rowb + i * 16;
                #pragma unroll
                for (int r = 0; r < 4; ++r) {
                    float v = acc[i][j][r] + bv;
                    if (RELU) v = fmaxf(v, 0.f);
                    if (tovt)          vtp[(gc - vc0) * 2048 + gr + r] = f2b(v);
                    else if (OUT == 0) Cf[(gr + r) * (long)ldc + gc] = v;
                    else               Cb[(gr + r) * (long)ldc + gc] = f2b(v);
                }
            }
        }
    }
}

// ---------------------------------------------------------------------------
// Fused flash attention.  One (b,h,64-q-block) per workgroup, 4 waves x 16 q.
// Q:[tok][ldq] bf16 (head offset pre-applied), K likewise, V from vt
// [512 d][2048 tok].  O -> att [tok][512] bf16.  scale=1/8 fused.
// CAUSAL: skips KV tiles beyond the diagonal (t <= qb) and masks only t==qb.
// ---------------------------------------------------------------------------
template<int CAUSAL>
__global__ __launch_bounds__(256)
void flash_kernel(const u16* __restrict__ Qp, int ldq,
                  const u16* __restrict__ Kp, int ldk,
                  const u16* __restrict__ Vt,
                  const int* __restrict__ tok,
                  u16* __restrict__ Op)
{
    __shared__ u16 QS[64 * 64];
    __shared__ u16 KS[64 * 64];
    __shared__ u16 VS[64 * 64];
    __shared__ u16 PS[4 * 16 * 64];
    __shared__ float MK[512];

    const int tid = threadIdx.x, lane = tid & 63, w = tid >> 6;
    const int l15 = lane & 15, l4 = lane >> 4;
    const int qb = blockIdx.x, bh = blockIdx.y;
    const int b = bh >> 3, h = bh & 7;

    const u16* Q = Qp + (long)(b * 512 + qb * 64) * ldq + h * 64;
    const u16* K = Kp + (long)(b * 512) * ldk + h * 64;
    const u16* V = Vt + (long)(h * 64) * 2048 + b * 512;
    u16* O = Op + (long)(b * 512 + qb * 64) * 512 + h * 64;

    {
        int t0 = tok[b * 512 + tid];
        int t1 = tok[b * 512 + 256 + tid];
        MK[tid]       = (t0 == 0) ? -1e9f : 0.f;
        MK[tid + 256] = (t1 == 0) ? -1e9f : 0.f;
    }
    {
        int r = tid >> 3;
        int c = (tid & 7) ^ (r & 7);
        GLD16(Q + (long)r * ldq + c * 8,        QS + tid * 8);
        GLD16(Q + (long)(r + 32) * ldq + c * 8, QS + 2048 + tid * 8);
    }

    f32x4 oacc[4];
    float mrun[4], lrun[4];
    #pragma unroll
    for (int j = 0; j < 4; ++j) oacc[j] = (f32x4){0.f, 0.f, 0.f, 0.f};
    #pragma unroll
    for (int r = 0; r < 4; ++r) { mrun[r] = -1e30f; lrun[r] = 0.f; }

    bhalf8 qa[2];
    const int tmax = CAUSAL ? qb : 7;

    for (int t = 0; t <= tmax; ++t) {
        {
            int r = tid >> 3;
            int c = (tid & 7) ^ (r & 7);
            GLD16(K + (long)(t * 64 + r) * ldk + c * 8,       KS + tid * 8);
            GLD16(K + (long)(t * 64 + 32 + r) * ldk + c * 8,  KS + 2048 + tid * 8);
            GLD16(V + (long)r * 2048 + t * 64 + c * 8,        VS + tid * 8);
            GLD16(V + (long)(r + 32) * 2048 + t * 64 + c * 8, VS + 2048 + tid * 8);
        }
        __syncthreads();
        if (t == 0) {
            #pragma unroll
            for (int kc = 0; kc < 2; ++kc) {
                int row = w * 16 + l15;
                qa[kc] = *(const bhalf8*)&QS[row * 64 + (((kc * 4 + l4) ^ (row & 7)) << 3)];
            }
        }
        // ---- S = Q K^T ----
        f32x4 sac[4];
        #pragma unroll
        for (int jj = 0; jj < 4; ++jj) sac[jj] = (f32x4){0.f, 0.f, 0.f, 0.f};
        bhalf8 kf[4][2];
        #pragma unroll
        for (int jj = 0; jj < 4; ++jj)
            #pragma unroll
            for (int kc = 0; kc < 2; ++kc) {
                int row = jj * 16 + l15;
                kf[jj][kc] = *(const bhalf8*)&KS[row * 64 + (((kc * 4 + l4) ^ (row & 7)) << 3)];
            }
        #pragma unroll
        for (int jj = 0; jj < 4; ++jj)
            #pragma unroll
            for (int kc = 0; kc < 2; ++kc)
                sac[jj] = __builtin_amdgcn_mfma_f32_16x16x32_bf16(qa[kc], kf[jj][kc], sac[jj], 0, 0, 0);

        // ---- scale + mask ----
        #pragma unroll
        for (int jj = 0; jj < 4; ++jj) {
            float mk = MK[t * 64 + jj * 16 + l15];
            #pragma unroll
            for (int r = 0; r < 4; ++r) {
                float mk2 = mk;
                if (CAUSAL && t == qb) {
                    int col = t * 64 + jj * 16 + l15;
                    int qr = qb * 64 + w * 16 + l4 * 4 + r;
                    if (col > qr) mk2 = -1e9f;
                }
                sac[jj][r] = sac[jj][r] * 0.125f + mk2;
            }
        }
        // ---- online softmax; P (bf16) -> per-wave swizzled LDS ----
        #pragma unroll
        for (int r = 0; r < 4; ++r) {
            float mx = fmaxf(fmaxf(sac[0][r], sac[1][r]), fmaxf(sac[2][r], sac[3][r]));
            mx = redmax16(mx);
            float mnew = fmaxf(mrun[r], mx);
            float alpha = __expf(mrun[r] - mnew);
            float sum = 0.f;
            int row_p = l4 * 4 + r;
            #pragma unroll
            for (int jj = 0; jj < 4; ++jj) {
                float pv = __expf(sac[jj][r] - mnew);
                sum += pv;
                int kv = jj * 16 + l15;
                PS[w * 1024 + row_p * 64 + ((((kv >> 3) ^ (row_p & 7)) << 3) | (kv & 7))] = f2b(pv);
            }
            sum = redsum16(sum);
            lrun[r] = lrun[r] * alpha + sum;
            mrun[r] = mnew;
            #pragma unroll
            for (int jd = 0; jd < 4; ++jd) oacc[jd][r] *= alpha;
        }
        // ---- O += P V ----
        bhalf8 pa[2], vf[4][2];
        #pragma unroll
        for (int kc = 0; kc < 2; ++kc) {
            int row = l15;
            pa[kc] = *(const bhalf8*)&PS[w * 1024 + row * 64 + (((kc * 4 + l4) ^ (row & 7)) << 3)];
        }
        #pragma unroll
        for (int jd = 0; jd < 4; ++jd)
            #pragma unroll
            for (int kc = 0; kc < 2; ++kc) {
                int row = jd * 16 + l15;
                vf[jd][kc] = *(const bhalf8*)&VS[row * 64 + (((kc * 4 + l4) ^ (row & 7)) << 3)];
            }
        #pragma unroll
        for (int jd = 0; jd < 4; ++jd)
            #pragma unroll
            for (int kc = 0; kc < 2; ++kc)
                oacc[jd] = __builtin_amdgcn_mfma_f32_16x16x32_bf16(pa[kc], vf[jd][kc], oacc[jd], 0, 0, 0);
        __syncthreads();
    }

    #pragma unroll
    for (int r = 0; r < 4; ++r) {
        float inv = 1.f / lrun[r];
        int row = w * 16 + l4 * 4 + r;
        #pragma unroll
        for (int jd = 0; jd < 4; ++jd)
            O[(long)row * 512 + jd * 16 + l15] = f2b(oacc[jd][r] * inv);
    }
}

// ---------------------------------------------------------------------------
// Prep: fp32 [R][C] -> bf16 [C][R] for a pack of matrices from two bases
// ---------------------------------------------------------------------------
__global__ __launch_bounds__(256)
void transpose_many(const float* __restrict__ inA, const float* __restrict__ inB,
                    int zsplit, int R, int C, u16* __restrict__ out)
{
    int z = blockIdx.z;
    const float* in = (z < zsplit) ? inA + (long)z * R * C
                                   : inB + (long)(z - zsplit) * R * C;
    u16* o = out + (long)z * R * C;
    __shared__ float tb[64][65];
    const int tr = blockIdx.y * 64, tc = blockIdx.x * 64;
    const int col = threadIdx.x & 63, r0 = threadIdx.x >> 6;
    #pragma unroll
    for (int p = 0; p < 16; ++p) {
        int row = r0 * 16 + p;
        tb[row][col] = in[(long)(tr + row) * C + tc + col];
    }
    __syncthreads();
    #pragma unroll
    for (int p = 0; p < 16; ++p) {
        int row = r0 * 16 + p;
        o[(long)(tc + row) * R + tr + col] = f2b(tb[col][row]);
    }
}

__global__ __launch_bounds__(256)
void convert_b16(const float4* __restrict__ in, u16* __restrict__ out, long n4)
{
    long i = (long)blockIdx.x * 256 + threadIdx.x;
    if (i >= n4) return;
    float4 v = in[i];
    uint2 p;
    p.x = (unsigned)f2b(v.x) | ((unsigned)f2b(v.y) << 16);
    p.y = (unsigned)f2b(v.z) | ((unsigned)f2b(v.w) << 16);
    *(uint2*)(out + i * 4) = p;
}

// ---------------------------------------------------------------------------
// Embedding (both sequences in one dispatch): x = emb[tok]*scale + pos
// ---------------------------------------------------------------------------
__global__ __launch_bounds__(256)
void embed_kernel(const int* __restrict__ tE, const int* __restrict__ tD,
                  const float* __restrict__ eE, const float* __restrict__ eD,
                  const float* __restrict__ pos,
                  float* __restrict__ xE, float* __restrict__ xD,
                  u16* __restrict__ bE, u16* __restrict__ bD, float scale)
{
    const int z = blockIdx.y;
    const int* tok = z ? tD : tE;
    const float* emb = z ? eD : eE;
    float* x = z ? xD : xE;
    u16* xb = z ? bD : bE;
    int row = blockIdx.x;
    int s = row & (S_ - 1);
    int t = tok[row];
    const float* er = emb + (long)t * D_;
    const float* pr = pos + (long)s * D_;
    float* o = x + (long)row * D_;
    u16*  ob = xb + (long)row * D_;
    int i = threadIdx.x;
    float v0 = er[i]       * scale + pr[i];
    float v1 = er[i + 256] * scale + pr[i + 256];
    o[i] = v0;        o[i + 256] = v1;
    ob[i] = f2b(v0);  ob[i + 256] = f2b(v1);
}

// ---------------------------------------------------------------------------
// x = LayerNorm(x + y) * g + b (fp32 state) + bf16 copy
// ---------------------------------------------------------------------------
__global__ __launch_bounds__(256)
void add_ln_kernel(float* __restrict__ x, const float* __restrict__ y,
                   u16* __restrict__ xb,
                   const float* __restrict__ g, const float* __restrict__ bb)
{
    long row = blockIdx.x;
    float* xr = x + row * D_;
    u16* xo = xb + row * D_;
    const float* yr = y + row * D_;
    int t = threadIdx.x, t2 = t + 256;

    float r0 = xr[t] + yr[t];
    float r1 = xr[t2] + yr[t2];
    float s = r0 + r1;
    float s2 = r0 * r0 + r1 * r1;
    #pragma unroll
    for (int i = 1; i < 64; i <<= 1) {
        s  += __shfl_xor(s, i);
        s2 += __shfl_xor(s2, i);
    }
    __shared__ float rs[4], rs2[4];
    int wid = t >> 6;
    if ((t & 63) == 0) { rs[wid] = s; rs2[wid] = s2; }
    __syncthreads();
    s  = rs[0] + rs[1] + rs[2] + rs[3];
    s2 = rs2[0] + rs2[1] + rs2[2] + rs2[3];

    float mean = s * (1.f / D_);
    float var  = s2 * (1.f / D_) - mean * mean;
    float inv  = rsqrtf(var + 1e-6f);
    float o0 = (r0 - mean) * inv * g[t]  + bb[t];
    float o1 = (r1 - mean) * inv * g[t2] + bb[t2];
    xr[t] = o0;       xr[t2] = o1;
    xo[t] = f2b(o0);  xo[t2] = f2b(o1);
}

// ---------------------------------------------------------------------------
extern "C" void kernel_launch(void* const* d_in, const int* in_sizes, int n_in,
                              void* d_out, int out_size, void* d_ws, size_t ws_size,
                              hipStream_t stream)
{
    const int*   enc_in     = (const int*)  d_in[0];
    const int*   dec_in     = (const int*)  d_in[1];
    const float* e_embed    = (const float*)d_in[2];
    const float* d_embed    = (const float*)d_in[3];
    const float* pos_enc    = (const float*)d_in[4];
    const float* enc_mha_W  = (const float*)d_in[5];
    const float* enc_mha_b  = (const float*)d_in[6];
    const float* enc_ln_g   = (const float*)d_in[7];
    const float* enc_ln_b   = (const float*)d_in[8];
    const float* enc_ffn_W1 = (const float*)d_in[9];
    const float* enc_ffn_b1 = (const float*)d_in[10];
    const float* enc_ffn_W2 = (const float*)d_in[11];
    const float* enc_ffn_b2 = (const float*)d_in[12];
    const float* dec_mha_W  = (const float*)d_in[13];
    const float* dec_mha_b  = (const float*)d_in[14];
    const float* dec_ln_g   = (const float*)d_in[15];
    const float* dec_ln_b   = (const float*)d_in[16];
    const float* dec_ffn_W1 = (const float*)d_in[17];
    const float* dec_ffn_b1 = (const float*)d_in[18];
    const float* dec_ffn_W2 = (const float*)d_in[19];
    const float* dec_ffn_b2 = (const float*)d_in[20];
    float* out = (float*)d_out;

    const int  BS  = B_ * S_;                 // 2048
    const long BSD = (long)BS * D_;
    const long DD  = (long)D_ * D_;
    const long DF  = (long)D_ * F_;

    char* p = (char*)d_ws;
    auto alloc = [&](long bytes) { char* r = p; p += (bytes + 255) & ~255L; return r; };
    float* e    = (float*)alloc(BSD * 4);
    float* dd   = (float*)alloc(BSD * 4);
    float* y    = (float*)alloc(BSD * 4);
    u16*   eb   = (u16*)  alloc(BSD * 2);
    u16*   ddb  = (u16*)  alloc(BSD * 2);
    u16*   qkv  = (u16*)  alloc((long)BS * 1536 * 2);
    u16*   att  = (u16*)  alloc(BSD * 2);
    u16*   vt   = (u16*)  alloc(BSD * 2);
    u16*   ffnh = (u16*)  alloc((long)BS * F_ * 2);
    u16*   wEmb = (u16*)  alloc((long)V_ * D_ * 2);
    u16*   wMha = (u16*)  alloc(72 * DD * 2);
    u16*   wF1  = (u16*)  alloc(12 * DF * 2);
    u16*   wF2  = (u16*)  alloc(12 * DF * 2);

    // ---- weight prep ----
    transpose_many<<<dim3(8, 8, 72), 256, 0, stream>>>(enc_mha_W, dec_mha_W, 24, 512, 512, wMha);
    transpose_many<<<dim3(32, 8, 12), 256, 0, stream>>>(enc_ffn_W1, dec_ffn_W1, 6, 512, 2048, wF1);
    transpose_many<<<dim3(8, 32, 12), 256, 0, stream>>>(enc_ffn_W2, dec_ffn_W2, 6, 2048, 512, wF2);
    convert_b16<<<16000, 256, 0, stream>>>((const float4*)d_embed, wEmb, (long)V_ * D_ / 4);

    const float scale = sqrtf((float)D_);
    embed_kernel<<<dim3(BS, 2), 256, 0, stream>>>(enc_in, dec_in, e_embed, d_embed,
                                                  pos_enc, e, dd, eb, ddb, scale);

    // kernel shapes:
    //  big:    2x2 waves, 64x64 wave tile -> 128x128 block, 256 thr
    //  skinny: 2x1 waves, 32x64 wave tile -> 64x64 block, 128 thr
    #define GEMM_BIG(grid, RELU, OUTT, A, Bp, bias, C, K, lda, ldb, ldc) \
        mfma_gemm<2,2,64,64,OUTT,RELU,1,0><<<grid, 256, 0, stream>>>(A, A, 1 << 30, Bp, bias, C, K, lda, ldb, ldc, nullptr, 0)
    #define GEMM_SK(grid, OUTT, A, Bp, bias, C, K, lda, ldb, ldc, vtp, vc0) \
        mfma_gemm<2,1,32,64,OUTT,0,1,0><<<grid, 128, 0, stream>>>(A, A, 1 << 30, Bp, bias, C, K, lda, ldb, ldc, vtp, vc0)

    // ---------------- encoder ----------------
    for (int l = 0; l < L_; ++l) {
        const u16* Wl = wMha + (long)l * 4 * DD;
        const float* bl = enc_mha_b + (long)l * 4 * D_;
        GEMM_SK(dim3(24, 32), 1, eb, Wl, bl, qkv, 512, 512, 512, 1536, vt, 1024);
        flash_kernel<0><<<dim3(8, 32), 256, 0, stream>>>(qkv, 1536, qkv + 512, 1536, vt, enc_in, att);
        GEMM_SK(dim3(8, 32), 0, att, Wl + 3 * DD, bl + 3 * D_, y, 512, 512, 512, 512, nullptr, 0);
        add_ln_kernel<<<BS, 256, 0, stream>>>(e, y, eb,
            enc_ln_g + (long)(l * 2) * D_, enc_ln_b + (long)(l * 2) * D_);
        GEMM_BIG(dim3(16, 16), 1, 1, eb, wF1 + (long)l * DF, enc_ffn_b1 + (long)l * F_,
                 ffnh, 512, 512, 512, 2048);
        GEMM_SK(dim3(8, 32), 0, ffnh, wF2 + (long)l * DF, enc_ffn_b2 + (long)l * D_,
                y, 2048, 2048, 2048, 512, nullptr, 0);
        add_ln_kernel<<<BS, 256, 0, stream>>>(e, y, eb,
            enc_ln_g + (long)(l * 2 + 1) * D_, enc_ln_b + (long)(l * 2 + 1) * D_);
    }

    // ---------------- decoder ----------------
    for (int l = 0; l < L_; ++l) {
        const u16* Wl = wMha + (long)(24 + l * 8) * DD;
        const float* bl = dec_mha_b + (long)l * 8 * D_;
        // self-attention (causal + dec pad)
        GEMM_SK(dim3(24, 32), 1, ddb, Wl, bl, qkv, 512, 512, 512, 1536, vt, 1024);
        flash_kernel<1><<<dim3(8, 32), 256, 0, stream>>>(qkv, 1536, qkv + 512, 1536, vt, dec_in, att);
        GEMM_SK(dim3(8, 32), 0, att, Wl + 3 * DD, bl + 3 * D_, y, 512, 512, 512, 512, nullptr, 0);
        add_ln_kernel<<<BS, 256, 0, stream>>>(dd, y, ddb,
            dec_ln_g + (long)(l * 3) * D_, dec_ln_b + (long)(l * 3) * D_);
        // cross-attention: fused q (from dd) + k,v (from e) projections
        mfma_gemm<2,1,32,64,1,0,1,1><<<dim3(24, 32), 128, 0, stream>>>(
            ddb, eb, 512, Wl + 4 * DD, bl + 4 * D_, qkv,
            512, 512, 512, 1536, vt, 1024);
        flash_kernel<0><<<dim3(8, 32), 256, 0, stream>>>(qkv, 1536, qkv + 512, 1536, vt, enc_in, att);
        GEMM_SK(dim3(8, 32), 0, att, Wl + 7 * DD, bl + 7 * D_, y, 512, 512, 512, 512, nullptr, 0);
        add_ln_kernel<<<BS, 256, 0, stream>>>(dd, y, ddb,
            dec_ln_g + (long)(l * 3 + 1) * D_, dec_ln_b + (long)(l * 3 + 1) * D_);
        // FFN
        GEMM_BIG(dim3(16, 16), 1, 1, ddb, wF1 + (long)(6 + l) * DF, dec_ffn_b1 + (long)l * F_,
                 ffnh, 512, 512, 512, 2048);
        GEMM_SK(dim3(8, 32), 0, ffnh, wF2 + (long)(6 + l) * DF, dec_ffn_b2 + (long)l * D_,
                y, 2048, 2048, 2048, 512, nullptr, 0);
        add_ln_kernel<<<BS, 256, 0, stream>>>(dd, y, ddb,
            dec_ln_g + (long)(l * 3 + 2) * D_, dec_ln_b + (long)(l * 3 + 2) * D_);
    }

    // ---------------- logits = dd @ d_embed^T (persistent B-panel, M-loop) ----
    mfma_gemm<2,2,64,64,0,0,8,0><<<dim3(250, 2), 256, 0, stream>>>(
        ddb, ddb, 1 << 30, wEmb, nullptr, out, 512, 512, 512, 32000, nullptr, 0);
}

// Round 5
// 1805.467 us; speedup vs baseline: 3.7485x; 1.0325x over previous
//
#include <hip/hip_runtime.h>
#include <hip/hip_bf16.h>
#include <math.h>

#define B_ 4
#define S_ 512
#define D_ 512
#define F_ 2048
#define L_ 6
#define H_ 8
#define V_ 32000

typedef unsigned short u16;
typedef __attribute__((ext_vector_type(8))) short bhalf8;   // 8 bf16 = 4 VGPRs
typedef __attribute__((ext_vector_type(4))) float f32x4;

__device__ __forceinline__ u16 f2b(float v) {
    unsigned x = __builtin_bit_cast(unsigned, v);
    return (u16)((x + 0x7FFFu + ((x >> 16) & 1u)) >> 16);   // RNE
}

#define GLD16(g, l) __builtin_amdgcn_global_load_lds( \
    (const __attribute__((address_space(1))) void*)(g), \
    (__attribute__((address_space(3))) void*)(l), 16, 0, 0)

__device__ __forceinline__ float redmax16(float v) {
    #pragma unroll
    for (int m = 1; m < 16; m <<= 1) v = fmaxf(v, __shfl_xor(v, m));
    return v;
}
__device__ __forceinline__ float redsum16(float v) {
    #pragma unroll
    for (int m = 1; m < 16; m <<= 1) v += __shfl_xor(v, m);
    return v;
}

// ---------------------------------------------------------------------------
// bf16 MFMA GEMM: C = A*B^T (+bias[col]) (+relu).
// A:[M][K] lda bf16; B:[N][K] ldb bf16 (K-contig). Wave tile WM x WN,
// block = NWR x NWC waves. XMAJOR: blockIdx.x indexes M (panel-sharing blocks
// dispatch consecutively). NT: nontemporal fp32 C stores (streaming C).
// VTT (requires BM=BN=64): blocks with bn>=vc0 write their tile TRANSPOSED
// through LDS to vtp[(col-vc0)][row] (stride 2048) with coalesced 64B runs.
// SPLITA: blocks with bn >= acut read A2 instead of A.
// ---------------------------------------------------------------------------
template<int NWR, int NWC, int WM, int WN, int OUT, int RELU, int MLOOP,
         int SPLITA, int XMAJOR, int NT, int VTT>
__global__ __launch_bounds__(NWR * NWC * 64)
void mfma_gemm(const u16* __restrict__ A, const u16* __restrict__ A2, int acut,
               const u16* __restrict__ B,
               const float* __restrict__ bias, void* __restrict__ Cv,
               int K, int lda, int ldb, int ldc,
               u16* __restrict__ vtp, int vc0)
{
    constexpr int BM = NWR * WM, BN = NWC * WN;
    constexpr int NW = NWR * NWC;
    constexpr int CH_A = BM / 16, CH_B = BN / 16, CH = CH_A + CH_B;
    constexpr int NI = WM / 16, NJ = WN / 16;

    __shared__ u16 As[BM * 32];
    __shared__ u16 Bs[BN * 32];
    __shared__ u16 TT[VTT ? 64 * 72 : 8];

    const int tid = threadIdx.x;
    const int wid = tid >> 6, lane = tid & 63;
    const int wrow = wid / NWC, wcol = wid % NWC;
    const long bn = (XMAJOR ? (long)blockIdx.y : (long)blockIdx.x) * BN;
    const long bmbase = (XMAJOR ? (long)blockIdx.x : (long)blockIdx.y);
    const int r4 = lane >> 2, c4 = lane & 3;
    const int l15 = lane & 15, l4 = lane >> 4;

    const u16* Ause = (SPLITA && bn >= acut) ? A2 : A;

    #pragma unroll 1
    for (int mi = 0; mi < MLOOP; ++mi) {
        const long bm = (bmbase * MLOOP + mi) * BM;

        f32x4 acc[NI][NJ];
        #pragma unroll
        for (int i = 0; i < NI; ++i)
            #pragma unroll
            for (int j = 0; j < NJ; ++j)
                acc[i][j] = (f32x4){0.f, 0.f, 0.f, 0.f};

        for (int k0 = 0; k0 < K; k0 += 32) {
            #pragma unroll
            for (int t = 0; t < CH / NW; ++t) {
                int c = wid + t * NW;
                if (c < CH_A) {
                    const u16* g = Ause + (bm + c * 16 + r4) * (long)lda + k0 + c4 * 8;
                    GLD16(g, As + c * 512 + lane * 8);
                } else {
                    int cb = c - CH_A;
                    const u16* g = B + (bn + cb * 16 + r4) * (long)ldb + k0 + c4 * 8;
                    GLD16(g, Bs + cb * 512 + lane * 8);
                }
            }
            __syncthreads();
            bhalf8 af[NI], bfr[NJ];
            #pragma unroll
            for (int i = 0; i < NI; ++i)
                af[i] = *(const bhalf8*)&As[(wrow * WM + i * 16 + l15) * 32 + l4 * 8];
            #pragma unroll
            for (int j = 0; j < NJ; ++j)
                bfr[j] = *(const bhalf8*)&Bs[(wcol * WN + j * 16 + l15) * 32 + l4 * 8];
            #pragma unroll
            for (int i = 0; i < NI; ++i)
                #pragma unroll
                for (int j = 0; j < NJ; ++j)
                    acc[i][j] = __builtin_amdgcn_mfma_f32_16x16x32_bf16(af[i], bfr[j], acc[i][j], 0, 0, 0);
            __syncthreads();
        }

        if (VTT && vtp != nullptr && bn >= vc0) {
            // transposed epilogue through LDS (BM=BN=64, 128 threads)
            #pragma unroll
            for (int j = 0; j < NJ; ++j) {
                const int c = wcol * WN + j * 16 + l15;
                const float bv = bias ? bias[bn + c] : 0.f;
                #pragma unroll
                for (int i = 0; i < NI; ++i) {
                    const int rw = wrow * WM + i * 16 + (l4 << 2);
                    #pragma unroll
                    for (int r = 0; r < 4; ++r)
                        TT[c * 72 + rw + r] = f2b(acc[i][j][r] + bv);
                }
            }
            __syncthreads();
            {
                const int c = tid >> 1, hh = tid & 1;
                const u16* src = &TT[c * 72 + hh * 32];
                u16* dst = &vtp[(bn - vc0 + c) * 2048 + bm + hh * 32];
                #pragma unroll
                for (int p = 0; p < 4; ++p)
                    *(uint4*)(dst + p * 8) = *(const uint4*)(src + p * 8);
            }
            __syncthreads();
            continue;
        }

        float* Cf = (float*)Cv;
        u16*   Cb = (u16*)Cv;
        const int rowb = wrow * WM + (l4 << 2);
        const int colb = wcol * WN + l15;
        #pragma unroll
        for (int j = 0; j < NJ; ++j) {
            const long gc = bn + colb + j * 16;
            const float bv = bias ? bias[gc] : 0.f;
            #pragma unroll
            for (int i = 0; i < NI; ++i) {
                const long gr = bm + rowb + i * 16;
                #pragma unroll
                for (int r = 0; r < 4; ++r) {
                    float v = acc[i][j][r] + bv;
                    if (RELU) v = fmaxf(v, 0.f);
                    if (OUT == 0) {
                        if (NT) __builtin_nontemporal_store(v, &Cf[(gr + r) * (long)ldc + gc]);
                        else    Cf[(gr + r) * (long)ldc + gc] = v;
                    } else {
                        Cb[(gr + r) * (long)ldc + gc] = f2b(v);
                    }
                }
            }
        }
    }
}

// ---------------------------------------------------------------------------
// Fused GEMM + residual + LayerNorm (N=512 full row per block).
// grid = M/16 blocks, 512 threads = 8 waves; wave w owns cols w*64..w*64+63.
// x (fp32) is residual input AND LN output; xb gets the bf16 copy.
// ---------------------------------------------------------------------------
__global__ __launch_bounds__(512)
void gemm_ln_kernel(const u16* __restrict__ A, const u16* __restrict__ B,
                    const float* __restrict__ bias,
                    float* __restrict__ x, u16* __restrict__ xb,
                    const float* __restrict__ g, const float* __restrict__ bb,
                    int K)
{
    __shared__ u16 As[16 * 32];
    __shared__ u16 Bs[512 * 32];
    __shared__ float red[2][16][8];
    __shared__ float mv[2][16];

    const int tid = threadIdx.x, w = tid >> 6, lane = tid & 63;
    const int l15 = lane & 15, l4 = lane >> 4;
    const int r4 = lane >> 2, c4 = lane & 3;
    const long bm = (long)blockIdx.x * 16;

    f32x4 acc[4];
    #pragma unroll
    for (int j = 0; j < 4; ++j) acc[j] = (f32x4){0.f, 0.f, 0.f, 0.f};

    for (int k0 = 0; k0 < K; k0 += 32) {
        #pragma unroll
        for (int t = 0; t < 5; ++t) {
            int c = w + t * 8;
            if (c < 33) {
                if (c == 0) {
                    GLD16(A + (bm + r4) * (long)K + k0 + c4 * 8, As + lane * 8);
                } else {
                    GLD16(B + ((c - 1) * 16 + r4) * (long)K + k0 + c4 * 8,
                          Bs + (c - 1) * 512 + lane * 8);
                }
            }
        }
        __syncthreads();
        bhalf8 af = *(const bhalf8*)&As[l15 * 32 + l4 * 8];
        #pragma unroll
        for (int j = 0; j < 4; ++j) {
            bhalf8 bf = *(const bhalf8*)&Bs[(w * 64 + j * 16 + l15) * 32 + l4 * 8];
            acc[j] = __builtin_amdgcn_mfma_f32_16x16x32_bf16(af, bf, acc[j], 0, 0, 0);
        }
        __syncthreads();
    }

    // epilogue: residual + row stats + LN
    float vbuf[4][4], s[4] = {0, 0, 0, 0}, s2[4] = {0, 0, 0, 0};
    #pragma unroll
    for (int j = 0; j < 4; ++j) {
        int col = w * 64 + j * 16 + l15;
        float bv = bias[col];
        #pragma unroll
        for (int r = 0; r < 4; ++r) {
            int row = l4 * 4 + r;
            float v = acc[j][r] + bv + x[(bm + row) * 512 + col];
            vbuf[j][r] = v;
            s[r] += v; s2[r] += v * v;
        }
    }
    #pragma unroll
    for (int r = 0; r < 4; ++r) { s[r] = redsum16(s[r]); s2[r] = redsum16(s2[r]); }
    if (l15 == 0) {
        #pragma unroll
        for (int r = 0; r < 4; ++r) {
            red[0][l4 * 4 + r][w] = s[r];
            red[1][l4 * 4 + r][w] = s2[r];
        }
    }
    __syncthreads();
    if (tid < 16) {
        float S = 0.f, S2 = 0.f;
        #pragma unroll
        for (int q = 0; q < 8; ++q) { S += red[0][tid][q]; S2 += red[1][tid][q]; }
        float mean = S * (1.f / 512.f);
        float var = S2 * (1.f / 512.f) - mean * mean;
        mv[0][tid] = mean;
        mv[1][tid] = rsqrtf(var + 1e-6f);
    }
    __syncthreads();
    #pragma unroll
    for (int j = 0; j < 4; ++j) {
        int col = w * 64 + j * 16 + l15;
        float gg = g[col], bbv = bb[col];
        #pragma unroll
        for (int r = 0; r < 4; ++r) {
            int row = l4 * 4 + r;
            float o = (vbuf[j][r] - mv[0][row]) * mv[1][row] * gg + bbv;
            x[(bm + row) * 512 + col] = o;
            xb[(bm + row) * 512 + col] = f2b(o);
        }
    }
}

// ---------------------------------------------------------------------------
// Fused flash attention (one (b,h,64-q-block) per workgroup, 4 waves x 16 q).
// ---------------------------------------------------------------------------
template<int CAUSAL>
__global__ __launch_bounds__(256)
void flash_kernel(const u16* __restrict__ Qp, int ldq,
                  const u16* __restrict__ Kp, int ldk,
                  const u16* __restrict__ Vt,
                  const int* __restrict__ tok,
                  u16* __restrict__ Op)
{
    __shared__ u16 QS[64 * 64];
    __shared__ u16 KS[64 * 64];
    __shared__ u16 VS[64 * 64];
    __shared__ u16 PS[4 * 16 * 64];
    __shared__ float MK[512];

    const int tid = threadIdx.x, lane = tid & 63, w = tid >> 6;
    const int l15 = lane & 15, l4 = lane >> 4;
    const int qb = blockIdx.x, bh = blockIdx.y;
    const int b = bh >> 3, h = bh & 7;

    const u16* Q = Qp + (long)(b * 512 + qb * 64) * ldq + h * 64;
    const u16* K = Kp + (long)(b * 512) * ldk + h * 64;
    const u16* V = Vt + (long)(h * 64) * 2048 + b * 512;
    u16* O = Op + (long)(b * 512 + qb * 64) * 512 + h * 64;

    {
        int t0 = tok[b * 512 + tid];
        int t1 = tok[b * 512 + 256 + tid];
        MK[tid]       = (t0 == 0) ? -1e9f : 0.f;
        MK[tid + 256] = (t1 == 0) ? -1e9f : 0.f;
    }
    {
        int r = tid >> 3;
        int c = (tid & 7) ^ (r & 7);
        GLD16(Q + (long)r * ldq + c * 8,        QS + tid * 8);
        GLD16(Q + (long)(r + 32) * ldq + c * 8, QS + 2048 + tid * 8);
    }

    f32x4 oacc[4];
    float mrun[4], lrun[4];
    #pragma unroll
    for (int j = 0; j < 4; ++j) oacc[j] = (f32x4){0.f, 0.f, 0.f, 0.f};
    #pragma unroll
    for (int r = 0; r < 4; ++r) { mrun[r] = -1e30f; lrun[r] = 0.f; }

    bhalf8 qa[2];
    const int tmax = CAUSAL ? qb : 7;

    for (int t = 0; t <= tmax; ++t) {
        {
            int r = tid >> 3;
            int c = (tid & 7) ^ (r & 7);
            GLD16(K + (long)(t * 64 + r) * ldk + c * 8,       KS + tid * 8);
            GLD16(K + (long)(t * 64 + 32 + r) * ldk + c * 8,  KS + 2048 + tid * 8);
            GLD16(V + (long)r * 2048 + t * 64 + c * 8,        VS + tid * 8);
            GLD16(V + (long)(r + 32) * 2048 + t * 64 + c * 8, VS + 2048 + tid * 8);
        }
        __syncthreads();
        if (t == 0) {
            #pragma unroll
            for (int kc = 0; kc < 2; ++kc) {
                int row = w * 16 + l15;
                qa[kc] = *(const bhalf8*)&QS[row * 64 + (((kc * 4 + l4) ^ (row & 7)) << 3)];
            }
        }
        // ---- S = Q K^T ----
        f32x4 sac[4];
        #pragma unroll
        for (int jj = 0; jj < 4; ++jj) sac[jj] = (f32x4){0.f, 0.f, 0.f, 0.f};
        bhalf8 kf[4][2];
        #pragma unroll
        for (int jj = 0; jj < 4; ++jj)
            #pragma unroll
            for (int kc = 0; kc < 2; ++kc) {
                int row = jj * 16 + l15;
                kf[jj][kc] = *(const bhalf8*)&KS[row * 64 + (((kc * 4 + l4) ^ (row & 7)) << 3)];
            }
        #pragma unroll
        for (int jj = 0; jj < 4; ++jj)
            #pragma unroll
            for (int kc = 0; kc < 2; ++kc)
                sac[jj] = __builtin_amdgcn_mfma_f32_16x16x32_bf16(qa[kc], kf[jj][kc], sac[jj], 0, 0, 0);

        // ---- scale + mask ----
        #pragma unroll
        for (int jj = 0; jj < 4; ++jj) {
            float mk = MK[t * 64 + jj * 16 + l15];
            #pragma unroll
            for (int r = 0; r < 4; ++r) {
                float mk2 = mk;
                if (CAUSAL && t == qb) {
                    int col = t * 64 + jj * 16 + l15;
                    int qr = qb * 64 + w * 16 + l4 * 4 + r;
                    if (col > qr) mk2 = -1e9f;
                }
                sac[jj][r] = sac[jj][r] * 0.125f + mk2;
            }
        }
        // ---- online softmax; P (bf16) -> per-wave swizzled LDS ----
        #pragma unroll
        for (int r = 0; r < 4; ++r) {
            float mx = fmaxf(fmaxf(sac[0][r], sac[1][r]), fmaxf(sac[2][r], sac[3][r]));
            mx = redmax16(mx);
            float mnew = fmaxf(mrun[r], mx);
            float alpha = __expf(mrun[r] - mnew);
            float sum = 0.f;
            int row_p = l4 * 4 + r;
            #pragma unroll
            for (int jj = 0; jj < 4; ++jj) {
                float pv = __expf(sac[jj][r] - mnew);
                sum += pv;
                int kv = jj * 16 + l15;
                PS[w * 1024 + row_p * 64 + ((((kv >> 3) ^ (row_p & 7)) << 3) | (kv & 7))] = f2b(pv);
            }
            sum = redsum16(sum);
            lrun[r] = lrun[r] * alpha + sum;
            mrun[r] = mnew;
            #pragma unroll
            for (int jd = 0; jd < 4; ++jd) oacc[jd][r] *= alpha;
        }
        // ---- O += P V ----
        bhalf8 pa[2], vf[4][2];
        #pragma unroll
        for (int kc = 0; kc < 2; ++kc) {
            int row = l15;
            pa[kc] = *(const bhalf8*)&PS[w * 1024 + row * 64 + (((kc * 4 + l4) ^ (row & 7)) << 3)];
        }
        #pragma unroll
        for (int jd = 0; jd < 4; ++jd)
            #pragma unroll
            for (int kc = 0; kc < 2; ++kc) {
                int row = jd * 16 + l15;
                vf[jd][kc] = *(const bhalf8*)&VS[row * 64 + (((kc * 4 + l4) ^ (row & 7)) << 3)];
            }
        #pragma unroll
        for (int jd = 0; jd < 4; ++jd)
            #pragma unroll
            for (int kc = 0; kc < 2; ++kc)
                oacc[jd] = __builtin_amdgcn_mfma_f32_16x16x32_bf16(pa[kc], vf[jd][kc], oacc[jd], 0, 0, 0);
        __syncthreads();
    }

    #pragma unroll
    for (int r = 0; r < 4; ++r) {
        float inv = 1.f / lrun[r];
        int row = w * 16 + l4 * 4 + r;
        #pragma unroll
        for (int jd = 0; jd < 4; ++jd)
            O[(long)row * 512 + jd * 16 + l15] = f2b(oacc[jd][r] * inv);
    }
}

// ---------------------------------------------------------------------------
// Prep: fp32 [R][C] -> bf16 [C][R] for a pack of matrices from two bases
// ---------------------------------------------------------------------------
__global__ __launch_bounds__(256)
void transpose_many(const float* __restrict__ inA, const float* __restrict__ inB,
                    int zsplit, int R, int C, u16* __restrict__ out)
{
    int z = blockIdx.z;
    const float* in = (z < zsplit) ? inA + (long)z * R * C
                                   : inB + (long)(z - zsplit) * R * C;
    u16* o = out + (long)z * R * C;
    __shared__ float tb[64][65];
    const int tr = blockIdx.y * 64, tc = blockIdx.x * 64;
    const int col = threadIdx.x & 63, r0 = threadIdx.x >> 6;
    #pragma unroll
    for (int p = 0; p < 16; ++p) {
        int row = r0 * 16 + p;
        tb[row][col] = in[(long)(tr + row) * C + tc + col];
    }
    __syncthreads();
    #pragma unroll
    for (int p = 0; p < 16; ++p) {
        int row = r0 * 16 + p;
        o[(long)(tc + row) * R + tr + col] = f2b(tb[col][row]);
    }
}

__global__ __launch_bounds__(256)
void convert_b16(const float4* __restrict__ in, u16* __restrict__ out, long n4)
{
    long i = (long)blockIdx.x * 256 + threadIdx.x;
    if (i >= n4) return;
    float4 v = in[i];
    uint2 p;
    p.x = (unsigned)f2b(v.x) | ((unsigned)f2b(v.y) << 16);
    p.y = (unsigned)f2b(v.z) | ((unsigned)f2b(v.w) << 16);
    *(uint2*)(out + i * 4) = p;
}

// ---------------------------------------------------------------------------
// Embedding (both sequences in one dispatch): x = emb[tok]*scale + pos
// ---------------------------------------------------------------------------
__global__ __launch_bounds__(256)
void embed_kernel(const int* __restrict__ tE, const int* __restrict__ tD,
                  const float* __restrict__ eE, const float* __restrict__ eD,
                  const float* __restrict__ pos,
                  float* __restrict__ xE, float* __restrict__ xD,
                  u16* __restrict__ bE, u16* __restrict__ bD, float scale)
{
    const int z = blockIdx.y;
    const int* tok = z ? tD : tE;
    const float* emb = z ? eD : eE;
    float* x = z ? xD : xE;
    u16* xb = z ? bD : bE;
    int row = blockIdx.x;
    int s = row & (S_ - 1);
    int t = tok[row];
    const float* er = emb + (long)t * D_;
    const float* pr = pos + (long)s * D_;
    float* o = x + (long)row * D_;
    u16*  ob = xb + (long)row * D_;
    int i = threadIdx.x;
    float v0 = er[i]       * scale + pr[i];
    float v1 = er[i + 256] * scale + pr[i + 256];
    o[i] = v0;        o[i + 256] = v1;
    ob[i] = f2b(v0);  ob[i + 256] = f2b(v1);
}

// ---------------------------------------------------------------------------
// x = LayerNorm(x + y) * g + b (fp32 state) + bf16 copy  (used after FFN2)
// ---------------------------------------------------------------------------
__global__ __launch_bounds__(256)
void add_ln_kernel(float* __restrict__ x, const float* __restrict__ y,
                   u16* __restrict__ xb,
                   const float* __restrict__ g, const float* __restrict__ bb)
{
    long row = blockIdx.x;
    float* xr = x + row * D_;
    u16* xo = xb + row * D_;
    const float* yr = y + row * D_;
    int t = threadIdx.x, t2 = t + 256;

    float r0 = xr[t] + yr[t];
    float r1 = xr[t2] + yr[t2];
    float s = r0 + r1;
    float s2 = r0 * r0 + r1 * r1;
    #pragma unroll
    for (int i = 1; i < 64; i <<= 1) {
        s  += __shfl_xor(s, i);
        s2 += __shfl_xor(s2, i);
    }
    __shared__ float rs[4], rs2[4];
    int wid = t >> 6;
    if ((t & 63) == 0) { rs[wid] = s; rs2[wid] = s2; }
    __syncthreads();
    s  = rs[0] + rs[1] + rs[2] + rs[3];
    s2 = rs2[0] + rs2[1] + rs2[2] + rs2[3];

    float mean = s * (1.f / D_);
    float var  = s2 * (1.f / D_) - mean * mean;
    float inv  = rsqrtf(var + 1e-6f);
    float o0 = (r0 - mean) * inv * g[t]  + bb[t];
    float o1 = (r1 - mean) * inv * g[t2] + bb[t2];
    xr[t] = o0;       xr[t2] = o1;
    xo[t] = f2b(o0);  xo[t2] = f2b(o1);
}

// ---------------------------------------------------------------------------
extern "C" void kernel_launch(void* const* d_in, const int* in_sizes, int n_in,
                              void* d_out, int out_size, void* d_ws, size_t ws_size,
                              hipStream_t stream)
{
    const int*   enc_in     = (const int*)  d_in[0];
    const int*   dec_in     = (const int*)  d_in[1];
    const float* e_embed    = (const float*)d_in[2];
    const float* d_embed    = (const float*)d_in[3];
    const float* pos_enc    = (const float*)d_in[4];
    const float* enc_mha_W  = (const float*)d_in[5];
    const float* enc_mha_b  = (const float*)d_in[6];
    const float* enc_ln_g   = (const float*)d_in[7];
    const float* enc_ln_b   = (const float*)d_in[8];
    const float* enc_ffn_W1 = (const float*)d_in[9];
    const float* enc_ffn_b1 = (const float*)d_in[10];
    const float* enc_ffn_W2 = (const float*)d_in[11];
    const float* enc_ffn_b2 = (const float*)d_in[12];
    const float* dec_mha_W  = (const float*)d_in[13];
    const float* dec_mha_b  = (const float*)d_in[14];
    const float* dec_ln_g   = (const float*)d_in[15];
    const float* dec_ln_b   = (const float*)d_in[16];
    const float* dec_ffn_W1 = (const float*)d_in[17];
    const float* dec_ffn_b1 = (const float*)d_in[18];
    const float* dec_ffn_W2 = (const float*)d_in[19];
    const float* dec_ffn_b2 = (const float*)d_in[20];
    float* out = (float*)d_out;

    const int  BS  = B_ * S_;                 // 2048
    const long BSD = (long)BS * D_;
    const long DD  = (long)D_ * D_;
    const long DF  = (long)D_ * F_;

    char* p = (char*)d_ws;
    auto alloc = [&](long bytes) { char* r = p; p += (bytes + 255) & ~255L; return r; };
    float* e    = (float*)alloc(BSD * 4);
    float* dd   = (float*)alloc(BSD * 4);
    float* y    = (float*)alloc(BSD * 4);
    u16*   eb   = (u16*)  alloc(BSD * 2);
    u16*   ddb  = (u16*)  alloc(BSD * 2);
    u16*   qkv  = (u16*)  alloc((long)BS * 1536 * 2);
    u16*   att  = (u16*)  alloc(BSD * 2);
    u16*   vt   = (u16*)  alloc(BSD * 2);
    u16*   ffnh = (u16*)  alloc((long)BS * F_ * 2);
    u16*   wEmb = (u16*)  alloc((long)V_ * D_ * 2);
    u16*   wMha = (u16*)  alloc(72 * DD * 2);
    u16*   wF1  = (u16*)  alloc(12 * DF * 2);
    u16*   wF2  = (u16*)  alloc(12 * DF * 2);

    // ---- weight prep ----
    transpose_many<<<dim3(8, 8, 72), 256, 0, stream>>>(enc_mha_W, dec_mha_W, 24, 512, 512, wMha);
    transpose_many<<<dim3(32, 8, 12), 256, 0, stream>>>(enc_ffn_W1, dec_ffn_W1, 6, 512, 2048, wF1);
    transpose_many<<<dim3(8, 32, 12), 256, 0, stream>>>(enc_ffn_W2, dec_ffn_W2, 6, 2048, 512, wF2);
    convert_b16<<<16000, 256, 0, stream>>>((const float4*)d_embed, wEmb, (long)V_ * D_ / 4);

    const float scale = sqrtf((float)D_);
    embed_kernel<<<dim3(BS, 2), 256, 0, stream>>>(enc_in, dec_in, e_embed, d_embed,
                                                  pos_enc, e, dd, eb, ddb, scale);

    //  skinny: 2x1 waves, 32x64 tile -> 64x64 block, 128 thr
    //  big:    2x2 waves, 64x64 tile -> 128x128 block, 256 thr
    #define GEMM_BIG(grid, RELU, OUTT, A, Bp, bias, C, K, lda, ldb, ldc) \
        mfma_gemm<2,2,64,64,OUTT,RELU,1,0,0,0,0><<<grid, 256, 0, stream>>>(A, A, 1 << 30, Bp, bias, C, K, lda, ldb, ldc, nullptr, 0)
    #define GEMM_SKV(grid, A, Bp, bias, C, K, lda, ldb, ldc, vtp, vc0) \
        mfma_gemm<2,1,32,64,1,0,1,0,0,0,1><<<grid, 128, 0, stream>>>(A, A, 1 << 30, Bp, bias, C, K, lda, ldb, ldc, vtp, vc0)
    #define GEMM_SK(grid, OUTT, A, Bp, bias, C, K, lda, ldb, ldc) \
        mfma_gemm<2,1,32,64,OUTT,0,1,0,0,0,0><<<grid, 128, 0, stream>>>(A, A, 1 << 30, Bp, bias, C, K, lda, ldb, ldc, nullptr, 0)

    // ---------------- encoder ----------------
    for (int l = 0; l < L_; ++l) {
        const u16* Wl = wMha + (long)l * 4 * DD;
        const float* bl = enc_mha_b + (long)l * 4 * D_;
        GEMM_SKV(dim3(24, 32), eb, Wl, bl, qkv, 512, 512, 512, 1536, vt, 1024);
        flash_kernel<0><<<dim3(8, 32), 256, 0, stream>>>(qkv, 1536, qkv + 512, 1536, vt, enc_in, att);
        gemm_ln_kernel<<<128, 512, 0, stream>>>(att, Wl + 3 * DD, bl + 3 * D_,
            e, eb, enc_ln_g + (long)(l * 2) * D_, enc_ln_b + (long)(l * 2) * D_, 512);
        GEMM_BIG(dim3(16, 16), 1, 1, eb, wF1 + (long)l * DF, enc_ffn_b1 + (long)l * F_,
                 ffnh, 512, 512, 512, 2048);
        GEMM_SK(dim3(8, 32), 0, ffnh, wF2 + (long)l * DF, enc_ffn_b2 + (long)l * D_,
                y, 2048, 2048, 2048, 512);
        add_ln_kernel<<<BS, 256, 0, stream>>>(e, y, eb,
            enc_ln_g + (long)(l * 2 + 1) * D_, enc_ln_b + (long)(l * 2 + 1) * D_);
    }

    // ---------------- decoder ----------------
    for (int l = 0; l < L_; ++l) {
        const u16* Wl = wMha + (long)(24 + l * 8) * DD;
        const float* bl = dec_mha_b + (long)l * 8 * D_;
        // self-attention (causal + dec pad)
        GEMM_SKV(dim3(24, 32), ddb, Wl, bl, qkv, 512, 512, 512, 1536, vt, 1024);
        flash_kernel<1><<<dim3(8, 32), 256, 0, stream>>>(qkv, 1536, qkv + 512, 1536, vt, dec_in, att);
        gemm_ln_kernel<<<128, 512, 0, stream>>>(att, Wl + 3 * DD, bl + 3 * D_,
            dd, ddb, dec_ln_g + (long)(l * 3) * D_, dec_ln_b + (long)(l * 3) * D_, 512);
        // cross-attention: fused q (from dd) + k,v (from e) projections
        mfma_gemm<2,1,32,64,1,0,1,1,0,0,1><<<dim3(24, 32), 128, 0, stream>>>(
            ddb, eb, 512, Wl + 4 * DD, bl + 4 * D_, qkv,
            512, 512, 512, 1536, vt, 1024);
        flash_kernel<0><<<dim3(8, 32), 256, 0, stream>>>(qkv, 1536, qkv + 512, 1536, vt, enc_in, att);
        gemm_ln_kernel<<<128, 512, 0, stream>>>(att, Wl + 7 * DD, bl + 7 * D_,
            dd, ddb, dec_ln_g + (long)(l * 3 + 1) * D_, dec_ln_b + (long)(l * 3 + 1) * D_, 512);
        // FFN
        GEMM_BIG(dim3(16, 16), 1, 1, ddb, wF1 + (long)(6 + l) * DF, dec_ffn_b1 + (long)l * F_,
                 ffnh, 512, 512, 512, 2048);
        GEMM_SK(dim3(8, 32), 0, ffnh, wF2 + (long)(6 + l) * DF, dec_ffn_b2 + (long)l * D_,
                y, 2048, 2048, 2048, 512);
        add_ln_kernel<<<BS, 256, 0, stream>>>(dd, y, ddb,
            dec_ln_g + (long)(l * 3 + 2) * D_, dec_ln_b + (long)(l * 3 + 2) * D_);
    }

    // ---------------- logits = dd @ d_embed^T ----------------
    // M-major grid (panel sharers dispatch consecutively) + nontemporal C
    mfma_gemm<2,2,64,64,0,0,1,0,1,1,0><<<dim3(16, 250), 256, 0, stream>>>(
        ddb, ddb, 1 << 30, wEmb, nullptr, out, 512, 512, 512, 32000, nullptr, 0);
}